// Round 2
// baseline (261.050 us; speedup 1.0000x reference)
//
#include <hip/hip_runtime.h>
#include <hip/hip_bf16.h>
#include <math.h>

// Problem constants (from reference)
#define B_SZ     16
#define N_PTS    8192
#define NPOINT   2048
#define KNBR     32
#define D_FEAT   61
#define C_IN     64            // D_FEAT + 3
#define P_BINS   5
#define C_OUT    128
#define M_ROWS   (B_SZ * NPOINT)          // 32768
#define K1       (C_IN * P_BINS)          // 320
#define EPSV     1e-5f

// ---------------------------------------------------------------------------
// Kernel 1: gather neighbors, radial binning, scatter-add into feature[M,320];
// also writes new_xyz.
// One block per (b, m). 64 threads: lane = channel.
// ---------------------------------------------------------------------------
__global__ __launch_bounds__(64) void gather_kernel(
    const float* __restrict__ xyz, const float* __restrict__ points,
    const float* __restrict__ lc, const int* __restrict__ nl,
    const int* __restrict__ didx, float* __restrict__ feat,
    float* __restrict__ newxyz)
{
    const int bid = blockIdx.x;          // b*NPOINT + m
    const int b   = bid >> 11;           // NPOINT = 2048
    const int tid = threadIdx.x;

    __shared__ int s_n[KNBR];
    __shared__ int s_bin[KNBR];

    if (tid < KNBR) {
        const int k = tid;
        const float* p = lc + ((size_t)bid * KNBR + k) * 3;
        float x = p[0], y = p[1];
        float dist = sqrtf(x * x + y * y);
        float d = fminf(dist / 1.5f, 0.99f);
        int bn = (int)floorf(d * 5.0f);
        bn = bn < 0 ? 0 : (bn > 4 ? 4 : bn);
        s_bin[k] = bn;
        s_n[k] = nl[(size_t)bid * KNBR + k];
    } else if (tid < KNBR + 3) {
        const int j = tid - KNBR;
        const int di = didx[bid];
        newxyz[(size_t)bid * 3 + j] = xyz[((size_t)b * N_PTS + di) * 3 + j];
    }
    __syncthreads();

    const int c = tid;                    // channel 0..63
    float a0 = 0.f, a1 = 0.f, a2 = 0.f, a3 = 0.f, a4 = 0.f;
    const size_t bo61 = (size_t)b * N_PTS * D_FEAT;
    const size_t bo3  = (size_t)b * N_PTS * 3;

    #pragma unroll 4
    for (int k = 0; k < KNBR; ++k) {
        const int n  = s_n[k];
        const int bn = s_bin[k];
        float v;
        if (c < D_FEAT) v = points[bo61 + (size_t)n * D_FEAT + c];
        else            v = xyz[bo3 + (size_t)n * 3 + (c - D_FEAT)];
        a0 += (bn == 0) ? v : 0.f;
        a1 += (bn == 1) ? v : 0.f;
        a2 += (bn == 2) ? v : 0.f;
        a3 += (bn == 3) ? v : 0.f;
        a4 += (bn == 4) ? v : 0.f;
    }

    float* fr = feat + (size_t)bid * K1;
    fr[c]          = a0;
    fr[64 + c]     = a1;
    fr[128 + c]    = a2;
    fr[192 + c]    = a3;
    fr[256 + c]    = a4;
}

// ---------------------------------------------------------------------------
// GEMM1: x1 = feat[32768,320] @ W1[320,128] + b1   (f32, VALU)
// Block: 256 threads, tile 64 rows x 128 cols, micro-tile 4x8.
// ---------------------------------------------------------------------------
__global__ __launch_bounds__(256) void gemm1_kernel(
    const float* __restrict__ A, const float* __restrict__ W,
    const float* __restrict__ bias, float* __restrict__ out)
{
    __shared__ float sA[64][33];
    __shared__ float sW[32][132];

    const int tid = threadIdx.x;
    const int ty = tid >> 4, tx = tid & 15;
    const int row0 = blockIdx.x * 64;

    float acc[4][8] = {};

    for (int kb = 0; kb < K1; kb += 32) {
        // stage A tile: 64x32 = 512 float4
        #pragma unroll
        for (int l = 0; l < 2; ++l) {
            int lin = tid + l * 256;
            int r = lin >> 3, c4 = lin & 7;
            float4 v = *(const float4*)&A[(size_t)(row0 + r) * K1 + kb + c4 * 4];
            sA[r][c4 * 4 + 0] = v.x; sA[r][c4 * 4 + 1] = v.y;
            sA[r][c4 * 4 + 2] = v.z; sA[r][c4 * 4 + 3] = v.w;
        }
        // stage W tile: 32x128 = 1024 float4
        #pragma unroll
        for (int l = 0; l < 4; ++l) {
            int lin = tid + l * 256;
            int r = lin >> 5, c4 = lin & 31;
            float4 v = *(const float4*)&W[(size_t)(kb + r) * C_OUT + c4 * 4];
            *(float4*)&sW[r][c4 * 4] = v;
        }
        __syncthreads();

        #pragma unroll
        for (int k = 0; k < 32; ++k) {
            float a[4];
            #pragma unroll
            for (int i = 0; i < 4; ++i) a[i] = sA[ty * 4 + i][k];
            float4 w0 = *(const float4*)&sW[k][tx * 8];
            float4 w1 = *(const float4*)&sW[k][tx * 8 + 4];
            float w[8] = {w0.x, w0.y, w0.z, w0.w, w1.x, w1.y, w1.z, w1.w};
            #pragma unroll
            for (int i = 0; i < 4; ++i)
                #pragma unroll
                for (int j = 0; j < 8; ++j)
                    acc[i][j] += a[i] * w[j];
        }
        __syncthreads();
    }

    float bj[8];
    #pragma unroll
    for (int j = 0; j < 8; ++j) bj[j] = bias[tx * 8 + j];
    #pragma unroll
    for (int i = 0; i < 4; ++i) {
        const size_t r = (size_t)(row0 + ty * 4 + i);
        float4 o0 = make_float4(acc[i][0] + bj[0], acc[i][1] + bj[1],
                                acc[i][2] + bj[2], acc[i][3] + bj[3]);
        float4 o1 = make_float4(acc[i][4] + bj[4], acc[i][5] + bj[5],
                                acc[i][6] + bj[6], acc[i][7] + bj[7]);
        *(float4*)&out[r * C_OUT + tx * 8]     = o0;
        *(float4*)&out[r * C_OUT + tx * 8 + 4] = o1;
    }
}

// ---------------------------------------------------------------------------
// Per-channel sum / sumsq over all 32768 rows (for BatchNorm batch stats).
// ---------------------------------------------------------------------------
__global__ __launch_bounds__(256) void stats_kernel(
    const float* __restrict__ X, float* __restrict__ sum, float* __restrict__ sumsq)
{
    const int c = threadIdx.x & 127;
    const int half = threadIdx.x >> 7;
    float s = 0.f, q = 0.f;
    for (int row = blockIdx.x * 2 + half; row < M_ROWS; row += gridDim.x * 2) {
        float v = X[(size_t)row * C_OUT + c];
        s += v;
        q += v * v;
    }
    __shared__ float ls[2][128], lq[2][128];
    ls[half][c] = s;
    lq[half][c] = q;
    __syncthreads();
    if (threadIdx.x < 128) {
        atomicAdd(&sum[c], ls[0][c] + ls[1][c]);
        atomicAdd(&sumsq[c], lq[0][c] + lq[1][c]);
    }
}

// ---------------------------------------------------------------------------
// GEMM2: y = relu(BN1(x1)) @ W2[128,128] + b2.  BN1+ReLU fused into A-load.
// ---------------------------------------------------------------------------
__global__ __launch_bounds__(256) void gemm2_kernel(
    const float* __restrict__ X,
    const float* __restrict__ sum1, const float* __restrict__ sq1,
    const float* __restrict__ g1, const float* __restrict__ be1,
    const float* __restrict__ W, const float* __restrict__ bias,
    float* __restrict__ out)
{
    __shared__ float sA[64][33];
    __shared__ float sW[32][132];
    __shared__ float sc[128], sh[128];

    const int tid = threadIdx.x;
    if (tid < 128) {
        float mu  = sum1[tid] * (1.0f / (float)M_ROWS);
        float var = sq1[tid] * (1.0f / (float)M_ROWS) - mu * mu;
        float iv  = 1.0f / sqrtf(var + EPSV);
        float s   = g1[tid] * iv;
        sc[tid] = s;
        sh[tid] = be1[tid] - mu * s;
    }
    __syncthreads();

    const int ty = tid >> 4, tx = tid & 15;
    const int row0 = blockIdx.x * 64;
    float acc[4][8] = {};

    for (int kb = 0; kb < C_OUT; kb += 32) {
        #pragma unroll
        for (int l = 0; l < 2; ++l) {
            int lin = tid + l * 256;
            int r = lin >> 3, c4 = lin & 7;
            int ch = kb + c4 * 4;
            float4 v = *(const float4*)&X[(size_t)(row0 + r) * C_OUT + ch];
            sA[r][c4 * 4 + 0] = fmaxf(0.f, sc[ch + 0] * v.x + sh[ch + 0]);
            sA[r][c4 * 4 + 1] = fmaxf(0.f, sc[ch + 1] * v.y + sh[ch + 1]);
            sA[r][c4 * 4 + 2] = fmaxf(0.f, sc[ch + 2] * v.z + sh[ch + 2]);
            sA[r][c4 * 4 + 3] = fmaxf(0.f, sc[ch + 3] * v.w + sh[ch + 3]);
        }
        #pragma unroll
        for (int l = 0; l < 4; ++l) {
            int lin = tid + l * 256;
            int r = lin >> 5, c4 = lin & 31;
            float4 v = *(const float4*)&W[(size_t)(kb + r) * C_OUT + c4 * 4];
            *(float4*)&sW[r][c4 * 4] = v;
        }
        __syncthreads();

        #pragma unroll
        for (int k = 0; k < 32; ++k) {
            float a[4];
            #pragma unroll
            for (int i = 0; i < 4; ++i) a[i] = sA[ty * 4 + i][k];
            float4 w0 = *(const float4*)&sW[k][tx * 8];
            float4 w1 = *(const float4*)&sW[k][tx * 8 + 4];
            float w[8] = {w0.x, w0.y, w0.z, w0.w, w1.x, w1.y, w1.z, w1.w};
            #pragma unroll
            for (int i = 0; i < 4; ++i)
                #pragma unroll
                for (int j = 0; j < 8; ++j)
                    acc[i][j] += a[i] * w[j];
        }
        __syncthreads();
    }

    float bj[8];
    #pragma unroll
    for (int j = 0; j < 8; ++j) bj[j] = bias[tx * 8 + j];
    #pragma unroll
    for (int i = 0; i < 4; ++i) {
        const size_t r = (size_t)(row0 + ty * 4 + i);
        float4 o0 = make_float4(acc[i][0] + bj[0], acc[i][1] + bj[1],
                                acc[i][2] + bj[2], acc[i][3] + bj[3]);
        float4 o1 = make_float4(acc[i][4] + bj[4], acc[i][5] + bj[5],
                                acc[i][6] + bj[6], acc[i][7] + bj[7]);
        *(float4*)&out[r * C_OUT + tx * 8]     = o0;
        *(float4*)&out[r * C_OUT + tx * 8 + 4] = o1;
    }
}

// ---------------------------------------------------------------------------
// Final: new_points = relu(BN2(y))
// ---------------------------------------------------------------------------
__global__ __launch_bounds__(256) void out_kernel(
    const float* __restrict__ Y,
    const float* __restrict__ sum2, const float* __restrict__ sq2,
    const float* __restrict__ g2, const float* __restrict__ be2,
    float* __restrict__ out)
{
    __shared__ float sc[128], sh[128];
    const int tid = threadIdx.x;
    if (tid < 128) {
        float mu  = sum2[tid] * (1.0f / (float)M_ROWS);
        float var = sq2[tid] * (1.0f / (float)M_ROWS) - mu * mu;
        float iv  = 1.0f / sqrtf(var + EPSV);
        float s   = g2[tid] * iv;
        sc[tid] = s;
        sh[tid] = be2[tid] - mu * s;
    }
    __syncthreads();

    const size_t e4 = (size_t)blockIdx.x * 256 + tid;   // float4 index
    float4 v = ((const float4*)Y)[e4];
    const int cb = (int)((e4 * 4) & 127);
    float4 r;
    r.x = fmaxf(0.f, sc[cb + 0] * v.x + sh[cb + 0]);
    r.y = fmaxf(0.f, sc[cb + 1] * v.y + sh[cb + 1]);
    r.z = fmaxf(0.f, sc[cb + 2] * v.z + sh[cb + 2]);
    r.w = fmaxf(0.f, sc[cb + 3] * v.w + sh[cb + 3]);
    ((float4*)out)[e4] = r;
}

// ---------------------------------------------------------------------------
extern "C" void kernel_launch(void* const* d_in, const int* in_sizes, int n_in,
                              void* d_out, int out_size, void* d_ws, size_t ws_size,
                              hipStream_t stream)
{
    const float* xyz    = (const float*)d_in[0];
    const float* points = (const float*)d_in[1];
    const float* lc     = (const float*)d_in[2];
    const int*   nl     = (const int*)d_in[3];
    // d_in[4] parameter_list: unused
    const int*   didx   = (const int*)d_in[5];
    const float* W1     = (const float*)d_in[6];
    const float* b1     = (const float*)d_in[7];
    const float* g1     = (const float*)d_in[8];
    const float* be1    = (const float*)d_in[9];
    const float* W2     = (const float*)d_in[10];
    const float* b2     = (const float*)d_in[11];
    const float* g2     = (const float*)d_in[12];
    const float* be2    = (const float*)d_in[13];

    float* out = (float*)d_out;
    float* ws  = (float*)d_ws;

    // workspace layout (floats)
    float* feat  = ws;                                   // 32768*320 = 10,485,760
    float* x1    = ws + (size_t)M_ROWS * K1;             //  4,194,304
    float* stats = x1 + (size_t)M_ROWS * C_OUT;          //  512
    float* y     = ws;                                   // reuse feat region after GEMM1

    hipMemsetAsync(stats, 0, 512 * sizeof(float), stream);

    gather_kernel<<<M_ROWS, 64, 0, stream>>>(xyz, points, lc, nl, didx, feat, out);
    gemm1_kernel<<<M_ROWS / 64, 256, 0, stream>>>(feat, W1, b1, x1);
    stats_kernel<<<256, 256, 0, stream>>>(x1, stats, stats + 128);
    gemm2_kernel<<<M_ROWS / 64, 256, 0, stream>>>(x1, stats, stats + 128,
                                                  g1, be1, W2, b2, y);
    stats_kernel<<<256, 256, 0, stream>>>(y, stats + 256, stats + 384);
    out_kernel<<<(M_ROWS * C_OUT) / (256 * 4), 256, 0, stream>>>(
        y, stats + 256, stats + 384, g2, be2, out + (size_t)M_ROWS * 3);
}

// Round 3
// 241.112 us; speedup vs baseline: 1.0827x; 1.0827x over previous
//
#include <hip/hip_runtime.h>
#include <hip/hip_bf16.h>
#include <math.h>

// Problem constants (from reference)
#define B_SZ     16
#define N_PTS    8192
#define NPOINT   2048
#define KNBR     32
#define D_FEAT   61
#define C_IN     64            // D_FEAT + 3
#define P_BINS   5
#define C_OUT    128
#define M_ROWS   (B_SZ * NPOINT)          // 32768
#define K1       (C_IN * P_BINS)          // 320
#define EPSV     1e-5f

typedef __attribute__((ext_vector_type(8))) short bf16x8;
typedef __attribute__((ext_vector_type(4))) float f32x4;

__device__ __forceinline__ unsigned short f2bf_rne(float v) {
    unsigned u = __float_as_uint(v);
    u += 0x7fffu + ((u >> 16) & 1u);
    return (unsigned short)(u >> 16);
}

// ---------------------------------------------------------------------------
// Kernel 1: gather neighbors, radial binning, scatter-add into feat[M,320] bf16;
// also writes new_xyz. One block per (b,m), 64 threads, lane = channel.
// XCD-aware swizzle: batch b -> XCD b/2 (2MB points slice x2 = 4MB = one L2).
// ---------------------------------------------------------------------------
__global__ __launch_bounds__(64) void gather_kernel(
    const float* __restrict__ xyz, const float* __restrict__ points,
    const float* __restrict__ lc, const int* __restrict__ nl,
    const int* __restrict__ didx, unsigned short* __restrict__ feat,
    float* __restrict__ newxyz)
{
    // bijective swizzle: g -> (b, m) with all blocks of batch b in XCD class b/2
    const int g    = blockIdx.x;
    const int xcd  = g & 7;
    const int slot = g >> 3;                 // 0..4095
    const int b    = 2 * xcd + (slot >> 11); // 0..15
    const int m    = slot & 2047;
    const int bid  = b * NPOINT + m;
    const int tid  = threadIdx.x;

    __shared__ int s_n[KNBR];
    __shared__ int s_bin[KNBR];

    if (tid < KNBR) {
        const int k = tid;
        const float* p = lc + ((size_t)bid * KNBR + k) * 3;
        float x = p[0], y = p[1];
        float dist = sqrtf(x * x + y * y);
        float d = fminf(dist / 1.5f, 0.99f);
        int bn = (int)floorf(d * 5.0f);
        bn = bn < 0 ? 0 : (bn > 4 ? 4 : bn);
        s_bin[k] = bn;
        s_n[k] = nl[(size_t)bid * KNBR + k];
    } else if (tid < KNBR + 3) {
        const int j = tid - KNBR;
        const int di = didx[bid];
        newxyz[(size_t)bid * 3 + j] = xyz[((size_t)b * N_PTS + di) * 3 + j];
    }
    __syncthreads();

    const int c = tid;                    // channel 0..63
    float a0 = 0.f, a1 = 0.f, a2 = 0.f, a3 = 0.f, a4 = 0.f;
    const size_t bo61 = (size_t)b * N_PTS * D_FEAT;
    const size_t bo3  = (size_t)b * N_PTS * 3;

    #pragma unroll 4
    for (int k = 0; k < KNBR; ++k) {
        const int n  = s_n[k];
        const int bn = s_bin[k];
        float v;
        if (c < D_FEAT) v = points[bo61 + (size_t)n * D_FEAT + c];
        else            v = xyz[bo3 + (size_t)n * 3 + (c - D_FEAT)];
        a0 += (bn == 0) ? v : 0.f;
        a1 += (bn == 1) ? v : 0.f;
        a2 += (bn == 2) ? v : 0.f;
        a3 += (bn == 3) ? v : 0.f;
        a4 += (bn == 4) ? v : 0.f;
    }

    unsigned short* fr = feat + (size_t)bid * K1;
    fr[c]       = f2bf_rne(a0);
    fr[64 + c]  = f2bf_rne(a1);
    fr[128 + c] = f2bf_rne(a2);
    fr[192 + c] = f2bf_rne(a3);
    fr[256 + c] = f2bf_rne(a4);
}

// ---------------------------------------------------------------------------
// Transpose+convert weights: src[K][N] f32 -> dst[N][K] bf16
// ---------------------------------------------------------------------------
__global__ __launch_bounds__(256) void convw_kernel(
    const float* __restrict__ src, unsigned short* __restrict__ dst, int K, int N)
{
    int idx = blockIdx.x * 256 + threadIdx.x;
    if (idx < K * N) {
        int k = idx / N, n = idx - k * N;
        dst[(size_t)n * K + k] = f2bf_rne(src[idx]);
    }
}

// ---------------------------------------------------------------------------
// GEMM1 (MFMA bf16): x1 = feat[32768,320] @ W1 + b1, f32 out.
// 256 thr = 4 waves; wave w owns rows [blk*64 + w*16, +16), all 128 cols.
// No LDS: A frag = 16B contiguous per lane; B from W1t[N][K] (L2-resident).
// Fragment layout (16x16x32): A: m=lane&15, k=(lane>>4)*8+j.
//                             B: n=lane&15, k=(lane>>4)*8+j.
//                             D: col=lane&15, row=(lane>>4)*4+i  [m89/m91]
// ---------------------------------------------------------------------------
__global__ __launch_bounds__(256) void gemm1_mfma(
    const unsigned short* __restrict__ A, const unsigned short* __restrict__ Wt,
    const float* __restrict__ bias, float* __restrict__ out)
{
    const int tid  = threadIdx.x;
    const int wave = tid >> 6, lane = tid & 63;
    const int lm = lane & 15, kg = lane >> 4;
    const int r0 = blockIdx.x * 64 + wave * 16;

    f32x4 acc[8] = {};
    const unsigned short* arow = A + (size_t)(r0 + lm) * K1 + kg * 8;

    #pragma unroll
    for (int kb = 0; kb < K1; kb += 32) {
        bf16x8 a = *(const bf16x8*)(arow + kb);
        #pragma unroll
        for (int nf = 0; nf < 8; ++nf) {
            bf16x8 bfr = *(const bf16x8*)(Wt + (size_t)(nf * 16 + lm) * K1 + kb + kg * 8);
            acc[nf] = __builtin_amdgcn_mfma_f32_16x16x32_bf16(a, bfr, acc[nf], 0, 0, 0);
        }
    }

    const int orow = r0 + kg * 4;
    #pragma unroll
    for (int nf = 0; nf < 8; ++nf) {
        const int col = nf * 16 + lm;
        const float bb = bias[col];
        #pragma unroll
        for (int i = 0; i < 4; ++i)
            out[(size_t)(orow + i) * C_OUT + col] = acc[nf][i] + bb;
    }
}

// ---------------------------------------------------------------------------
// Per-channel sum / sumsq over all 32768 rows (BatchNorm batch stats).
// ---------------------------------------------------------------------------
__global__ __launch_bounds__(256) void stats_kernel(
    const float* __restrict__ X, float* __restrict__ sum, float* __restrict__ sumsq)
{
    const int c = threadIdx.x & 127;
    const int half = threadIdx.x >> 7;
    float s = 0.f, q = 0.f;
    for (int row = blockIdx.x * 2 + half; row < M_ROWS; row += gridDim.x * 2) {
        float v = X[(size_t)row * C_OUT + c];
        s += v;
        q += v * v;
    }
    __shared__ float ls[2][128], lq[2][128];
    ls[half][c] = s;
    lq[half][c] = q;
    __syncthreads();
    if (threadIdx.x < 128) {
        atomicAdd(&sum[c], ls[0][c] + ls[1][c]);
        atomicAdd(&sumsq[c], lq[0][c] + lq[1][c]);
    }
}

// ---------------------------------------------------------------------------
// GEMM2 (MFMA bf16): y = relu(BN1(x1)) @ W2 + b2. BN1+ReLU fused into A-load.
// ---------------------------------------------------------------------------
__global__ __launch_bounds__(256) void gemm2_mfma(
    const float* __restrict__ X,
    const float* __restrict__ sum1, const float* __restrict__ sq1,
    const float* __restrict__ g1, const float* __restrict__ be1,
    const unsigned short* __restrict__ Wt, const float* __restrict__ bias,
    float* __restrict__ out)
{
    __shared__ float sc[128], sh[128];
    const int tid = threadIdx.x;
    if (tid < 128) {
        float mu  = sum1[tid] * (1.0f / (float)M_ROWS);
        float var = sq1[tid] * (1.0f / (float)M_ROWS) - mu * mu;
        float iv  = 1.0f / sqrtf(var + EPSV);
        float s   = g1[tid] * iv;
        sc[tid] = s;
        sh[tid] = be1[tid] - mu * s;
    }
    __syncthreads();

    const int wave = tid >> 6, lane = tid & 63;
    const int lm = lane & 15, kg = lane >> 4;
    const int r0 = blockIdx.x * 64 + wave * 16;
    const float* xrow = X + (size_t)(r0 + lm) * C_OUT;

    f32x4 acc[8] = {};

    #pragma unroll
    for (int kb = 0; kb < C_OUT; kb += 32) {
        const int k0 = kb + kg * 8;
        bf16x8 a;
        #pragma unroll
        for (int j = 0; j < 8; ++j) {
            float v = fmaxf(0.f, sc[k0 + j] * xrow[k0 + j] + sh[k0 + j]);
            a[j] = (short)f2bf_rne(v);
        }
        #pragma unroll
        for (int nf = 0; nf < 8; ++nf) {
            bf16x8 bfr = *(const bf16x8*)(Wt + (size_t)(nf * 16 + lm) * C_OUT + k0);
            acc[nf] = __builtin_amdgcn_mfma_f32_16x16x32_bf16(a, bfr, acc[nf], 0, 0, 0);
        }
    }

    const int orow = r0 + kg * 4;
    #pragma unroll
    for (int nf = 0; nf < 8; ++nf) {
        const int col = nf * 16 + lm;
        const float bb = bias[col];
        #pragma unroll
        for (int i = 0; i < 4; ++i)
            out[(size_t)(orow + i) * C_OUT + col] = acc[nf][i] + bb;
    }
}

// ---------------------------------------------------------------------------
// Final: new_points = relu(BN2(y))
// ---------------------------------------------------------------------------
__global__ __launch_bounds__(256) void out_kernel(
    const float* __restrict__ Y,
    const float* __restrict__ sum2, const float* __restrict__ sq2,
    const float* __restrict__ g2, const float* __restrict__ be2,
    float* __restrict__ out)
{
    __shared__ float sc[128], sh[128];
    const int tid = threadIdx.x;
    if (tid < 128) {
        float mu  = sum2[tid] * (1.0f / (float)M_ROWS);
        float var = sq2[tid] * (1.0f / (float)M_ROWS) - mu * mu;
        float iv  = 1.0f / sqrtf(var + EPSV);
        float s   = g2[tid] * iv;
        sc[tid] = s;
        sh[tid] = be2[tid] - mu * s;
    }
    __syncthreads();

    const size_t e4 = (size_t)blockIdx.x * 256 + tid;   // float4 index
    float4 v = ((const float4*)Y)[e4];
    const int cb = (int)((e4 * 4) & 127);
    float4 r;
    r.x = fmaxf(0.f, sc[cb + 0] * v.x + sh[cb + 0]);
    r.y = fmaxf(0.f, sc[cb + 1] * v.y + sh[cb + 1]);
    r.z = fmaxf(0.f, sc[cb + 2] * v.z + sh[cb + 2]);
    r.w = fmaxf(0.f, sc[cb + 3] * v.w + sh[cb + 3]);
    ((float4*)out)[e4] = r;
}

// ---------------------------------------------------------------------------
extern "C" void kernel_launch(void* const* d_in, const int* in_sizes, int n_in,
                              void* d_out, int out_size, void* d_ws, size_t ws_size,
                              hipStream_t stream)
{
    const float* xyz    = (const float*)d_in[0];
    const float* points = (const float*)d_in[1];
    const float* lc     = (const float*)d_in[2];
    const int*   nl     = (const int*)d_in[3];
    // d_in[4] parameter_list: unused
    const int*   didx   = (const int*)d_in[5];
    const float* W1     = (const float*)d_in[6];
    const float* b1     = (const float*)d_in[7];
    const float* g1     = (const float*)d_in[8];
    const float* be1    = (const float*)d_in[9];
    const float* W2     = (const float*)d_in[10];
    const float* b2     = (const float*)d_in[11];
    const float* g2     = (const float*)d_in[12];
    const float* be2    = (const float*)d_in[13];

    float* out = (float*)d_out;
    char*  ws  = (char*)d_ws;

    // workspace layout (bytes)
    unsigned short* feat = (unsigned short*)ws;                   // 20,971,520 B
    float*          x1   = (float*)(ws + 20971520);               // 16,777,216 B
    unsigned short* W1t  = (unsigned short*)(ws + 37748736);      //     81,920 B
    unsigned short* W2t  = (unsigned short*)(ws + 37830656);      //     32,768 B
    float*          st   = (float*)(ws + 37863424);               //      2,048 B
    float*          y    = (float*)ws;                            // reuse feat region

    hipMemsetAsync(st, 0, 512 * sizeof(float), stream);
    convw_kernel<<<(K1 * C_OUT + 255) / 256, 256, 0, stream>>>(W1, W1t, K1, C_OUT);
    convw_kernel<<<(C_OUT * C_OUT + 255) / 256, 256, 0, stream>>>(W2, W2t, C_OUT, C_OUT);

    gather_kernel<<<M_ROWS, 64, 0, stream>>>(xyz, points, lc, nl, didx, feat, out);
    gemm1_mfma<<<M_ROWS / 64, 256, 0, stream>>>(feat, W1t, b1, x1);
    stats_kernel<<<256, 256, 0, stream>>>(x1, st, st + 128);
    gemm2_mfma<<<M_ROWS / 64, 256, 0, stream>>>(x1, st, st + 128, g1, be1, W2t, b2, y);
    stats_kernel<<<256, 256, 0, stream>>>(y, st + 256, st + 384);
    out_kernel<<<(M_ROWS * C_OUT) / (256 * 4), 256, 0, stream>>>(
        y, st + 256, st + 384, g2, be2, out + (size_t)M_ROWS * 3);
}

// Round 4
// 226.977 us; speedup vs baseline: 1.1501x; 1.0623x over previous
//
#include <hip/hip_runtime.h>
#include <hip/hip_bf16.h>
#include <math.h>

// Problem constants (from reference)
#define B_SZ     16
#define N_PTS    8192
#define NPOINT   2048
#define KNBR     32
#define D_FEAT   61
#define C_IN     64            // D_FEAT + 3
#define P_BINS   5
#define C_OUT    128
#define M_ROWS   (B_SZ * NPOINT)          // 32768
#define K1       (C_IN * P_BINS)          // 320
#define EPSV     1e-5f

typedef __attribute__((ext_vector_type(8))) short bf16x8;
typedef __attribute__((ext_vector_type(4))) float f32x4;

__device__ __forceinline__ unsigned short f2bf_rne(float v) {
    unsigned u = __float_as_uint(v);
    u += 0x7fffu + ((u >> 16) & 1u);
    return (unsigned short)(u >> 16);
}

// ---------------------------------------------------------------------------
// Prep: W1[320][128]->W1t[128][320] bf16, W2[128][128]->W2t[128][128] bf16,
// zero the 512-float stats block. One dispatch.
// ---------------------------------------------------------------------------
__global__ __launch_bounds__(256) void prep_kernel(
    const float* __restrict__ W1, const float* __restrict__ W2,
    unsigned short* __restrict__ W1t, unsigned short* __restrict__ W2t,
    float* __restrict__ st)
{
    const int gid = blockIdx.x * 256 + threadIdx.x;
    if (gid < 512) st[gid] = 0.f;
    if (gid < K1 * C_OUT) {
        int k = gid >> 7, n = gid & 127;
        W1t[(size_t)n * K1 + k] = f2bf_rne(W1[gid]);
    } else {
        int i = gid - K1 * C_OUT;
        if (i < C_OUT * C_OUT) {
            int k = i >> 7, n = i & 127;
            W2t[(size_t)n * C_OUT + k] = f2bf_rne(W2[i]);
        }
    }
}

// ---------------------------------------------------------------------------
// Gather: 4 points/block (1 per wave). Per wave: counting-sort 32 neighbors by
// radial bin (ballot/popc), then single-accumulator runs with SGPR-base gather
// addresses (readfirstlane). Writes feat[M][320] bf16 + new_xyz.
// XCD swizzle: batch b pinned to XCD b/2 (4 MB points slice per L2).
// ---------------------------------------------------------------------------
__global__ __launch_bounds__(256) void gather_kernel(
    const float* __restrict__ xyz, const float* __restrict__ points,
    const float* __restrict__ lc, const int* __restrict__ nl,
    const int* __restrict__ didx, unsigned short* __restrict__ feat,
    float* __restrict__ newxyz)
{
    const int g    = blockIdx.x;             // 0..8191
    const int xcd  = g & 7;
    const int slot = g >> 3;                 // 0..1023
    const int b    = 2 * xcd + (slot >> 9);  // 512 blocks per batch
    const int m    = (slot & 511) * 4 + (threadIdx.x >> 6);
    const int bid  = b * NPOINT + m;
    const int wave = threadIdx.x >> 6;
    const int lane = threadIdx.x & 63;

    __shared__ int s_srt[4][32];
    __shared__ int s_end[4][8];

    // --- prologue: bins + counting sort (lanes 32-63 mirror lanes 0-31) ---
    const size_t nbase = (size_t)bid * KNBR;
    const int k = lane & 31;
    float x = lc[(nbase + k) * 3 + 0];
    float y = lc[(nbase + k) * 3 + 1];
    float d = fminf(sqrtf(x * x + y * y) * (1.0f / 1.5f), 0.99f);
    int bin = (int)(d * 5.0f);
    bin = bin > 4 ? 4 : (bin < 0 ? 0 : bin);
    const int n = nl[nbase + k];

    unsigned m0 = (unsigned)__ballot(bin == 0);
    unsigned m1 = (unsigned)__ballot(bin == 1);
    unsigned m2 = (unsigned)__ballot(bin == 2);
    unsigned m3 = (unsigned)__ballot(bin == 3);
    unsigned m4b = (unsigned)__ballot(bin == 4);
    int c0n = __popc(m0), c1n = __popc(m1), c2n = __popc(m2), c3n = __popc(m3);

    int start = (bin > 0 ? c0n : 0) + (bin > 1 ? c1n : 0) +
                (bin > 2 ? c2n : 0) + (bin > 3 ? c3n : 0);
    unsigned mymask = m0;
    mymask = bin == 1 ? m1 : mymask;
    mymask = bin == 2 ? m2 : mymask;
    mymask = bin == 3 ? m3 : mymask;
    mymask = bin == 4 ? m4b : mymask;
    const int pos = start + __popc(mymask & ((1u << k) - 1u));

    if (lane < 32) s_srt[wave][pos] = n;
    if (lane == 0) {
        int e = 0;
        s_end[wave][0] = (e += c0n);
        s_end[wave][1] = (e += c1n);
        s_end[wave][2] = (e += c2n);
        s_end[wave][3] = (e += c3n);
        s_end[wave][4] = 32;
    }
    if (lane >= 32 && lane < 35) {
        const int di = didx[bid];
        const int j = lane - 32;
        newxyz[(size_t)bid * 3 + j] = xyz[((size_t)b * N_PTS + di) * 3 + j];
    }

    // --- main: sorted-run accumulation, scalar-base gather loads ---
    const int c = lane;
    const float* __restrict__ pbase = points + (size_t)b * N_PTS * D_FEAT;
    const float* __restrict__ xbase = xyz + (size_t)b * N_PTS * 3;
    unsigned short* fr = feat + (size_t)bid * K1;

    int e = 0;
    #pragma unroll
    for (int bb = 0; bb < 5; ++bb) {
        const int eend = __builtin_amdgcn_readfirstlane(s_end[wave][bb]);
        float acc = 0.f;
        for (; e < eend; ++e) {
            const int nn = __builtin_amdgcn_readfirstlane(s_srt[wave][e]);
            float v;
            if (c < D_FEAT) v = pbase[(size_t)nn * D_FEAT + c];
            else            v = xbase[(size_t)nn * 3 + (c - D_FEAT)];
            acc += v;
        }
        fr[bb * 64 + c] = f2bf_rne(acc);
    }
}

// ---------------------------------------------------------------------------
// GEMM1 (MFMA bf16, no LDS tiles): x1 = feat @ W1 + b1, f32 out.
// 4 waves/block, wave = 16 rows x 128 cols. Fused per-channel sum/sumsq.
// Fragment layout (16x16x32): A/B: k=(lane>>4)*8+j; D: col=lane&15,row=(lane>>4)*4+i.
// ---------------------------------------------------------------------------
__global__ __launch_bounds__(256) void gemm1_mfma(
    const unsigned short* __restrict__ A, const unsigned short* __restrict__ Wt,
    const float* __restrict__ bias, float* __restrict__ out,
    float* __restrict__ sum, float* __restrict__ sumsq)
{
    const int tid  = threadIdx.x;
    const int wave = tid >> 6, lane = tid & 63;
    const int lm = lane & 15, kg = lane >> 4;
    const int r0 = blockIdx.x * 64 + wave * 16;

    f32x4 acc[8] = {};
    const unsigned short* arow = A + (size_t)(r0 + lm) * K1 + kg * 8;

    #pragma unroll
    for (int kb = 0; kb < K1; kb += 32) {
        bf16x8 a = *(const bf16x8*)(arow + kb);
        #pragma unroll
        for (int nf = 0; nf < 8; ++nf) {
            bf16x8 bfr = *(const bf16x8*)(Wt + (size_t)(nf * 16 + lm) * K1 + kb + kg * 8);
            acc[nf] = __builtin_amdgcn_mfma_f32_16x16x32_bf16(a, bfr, acc[nf], 0, 0, 0);
        }
    }

    __shared__ float s_s[4][128], s_q[4][128];
    const int orow = r0 + kg * 4;
    #pragma unroll
    for (int nf = 0; nf < 8; ++nf) {
        const int col = nf * 16 + lm;
        const float bb = bias[col];
        float ls = 0.f, lq = 0.f;
        #pragma unroll
        for (int i = 0; i < 4; ++i) {
            float v = acc[nf][i] + bb;
            out[(size_t)(orow + i) * C_OUT + col] = v;
            ls += v; lq += v * v;
        }
        ls += __shfl_xor(ls, 16); ls += __shfl_xor(ls, 32);
        lq += __shfl_xor(lq, 16); lq += __shfl_xor(lq, 32);
        if (kg == 0) { s_s[wave][col] = ls; s_q[wave][col] = lq; }
    }
    __syncthreads();
    if (tid < 128) {
        float ts = s_s[0][tid] + s_s[1][tid] + s_s[2][tid] + s_s[3][tid];
        float tq = s_q[0][tid] + s_q[1][tid] + s_q[2][tid] + s_q[3][tid];
        atomicAdd(&sum[tid], ts);
        atomicAdd(&sumsq[tid], tq);
    }
}

// ---------------------------------------------------------------------------
// GEMM2 (MFMA bf16): y = relu(BN1(x1)) @ W2 + b2, BN1 fused into A-load,
// fused per-channel sum/sumsq for BN2.
// ---------------------------------------------------------------------------
__global__ __launch_bounds__(256) void gemm2_mfma(
    const float* __restrict__ X,
    const float* __restrict__ sum1, const float* __restrict__ sq1,
    const float* __restrict__ g1, const float* __restrict__ be1,
    const unsigned short* __restrict__ Wt, const float* __restrict__ bias,
    float* __restrict__ out, float* __restrict__ sum, float* __restrict__ sumsq)
{
    __shared__ float sc[128], sh[128];
    __shared__ float s_s[4][128], s_q[4][128];
    const int tid = threadIdx.x;
    if (tid < 128) {
        float mu  = sum1[tid] * (1.0f / (float)M_ROWS);
        float var = sq1[tid] * (1.0f / (float)M_ROWS) - mu * mu;
        float iv  = 1.0f / sqrtf(var + EPSV);
        float s   = g1[tid] * iv;
        sc[tid] = s;
        sh[tid] = be1[tid] - mu * s;
    }
    __syncthreads();

    const int wave = tid >> 6, lane = tid & 63;
    const int lm = lane & 15, kg = lane >> 4;
    const int r0 = blockIdx.x * 64 + wave * 16;
    const float* xrow = X + (size_t)(r0 + lm) * C_OUT;

    f32x4 acc[8] = {};

    #pragma unroll
    for (int kb = 0; kb < C_OUT; kb += 32) {
        const int k0 = kb + kg * 8;
        f32x4 v0 = *(const f32x4*)(xrow + k0);
        f32x4 v1 = *(const f32x4*)(xrow + k0 + 4);
        bf16x8 a;
        #pragma unroll
        for (int j = 0; j < 4; ++j) {
            a[j]     = (short)f2bf_rne(fmaxf(0.f, sc[k0 + j] * v0[j] + sh[k0 + j]));
            a[4 + j] = (short)f2bf_rne(fmaxf(0.f, sc[k0 + 4 + j] * v1[j] + sh[k0 + 4 + j]));
        }
        #pragma unroll
        for (int nf = 0; nf < 8; ++nf) {
            bf16x8 bfr = *(const bf16x8*)(Wt + (size_t)(nf * 16 + lm) * C_OUT + k0);
            acc[nf] = __builtin_amdgcn_mfma_f32_16x16x32_bf16(a, bfr, acc[nf], 0, 0, 0);
        }
    }

    const int orow = r0 + kg * 4;
    #pragma unroll
    for (int nf = 0; nf < 8; ++nf) {
        const int col = nf * 16 + lm;
        const float bb = bias[col];
        float ls = 0.f, lq = 0.f;
        #pragma unroll
        for (int i = 0; i < 4; ++i) {
            float v = acc[nf][i] + bb;
            out[(size_t)(orow + i) * C_OUT + col] = v;
            ls += v; lq += v * v;
        }
        ls += __shfl_xor(ls, 16); ls += __shfl_xor(ls, 32);
        lq += __shfl_xor(lq, 16); lq += __shfl_xor(lq, 32);
        if (kg == 0) { s_s[wave][col] = ls; s_q[wave][col] = lq; }
    }
    __syncthreads();
    if (tid < 128) {
        float ts = s_s[0][tid] + s_s[1][tid] + s_s[2][tid] + s_s[3][tid];
        float tq = s_q[0][tid] + s_q[1][tid] + s_q[2][tid] + s_q[3][tid];
        atomicAdd(&sum[tid], ts);
        atomicAdd(&sumsq[tid], tq);
    }
}

// ---------------------------------------------------------------------------
// Final: new_points = relu(BN2(y))
// ---------------------------------------------------------------------------
__global__ __launch_bounds__(256) void out_kernel(
    const float* __restrict__ Y,
    const float* __restrict__ sum2, const float* __restrict__ sq2,
    const float* __restrict__ g2, const float* __restrict__ be2,
    float* __restrict__ out)
{
    __shared__ float sc[128], sh[128];
    const int tid = threadIdx.x;
    if (tid < 128) {
        float mu  = sum2[tid] * (1.0f / (float)M_ROWS);
        float var = sq2[tid] * (1.0f / (float)M_ROWS) - mu * mu;
        float iv  = 1.0f / sqrtf(var + EPSV);
        float s   = g2[tid] * iv;
        sc[tid] = s;
        sh[tid] = be2[tid] - mu * s;
    }
    __syncthreads();

    const size_t e4 = (size_t)blockIdx.x * 256 + tid;   // float4 index
    float4 v = ((const float4*)Y)[e4];
    const int cb = (int)((e4 * 4) & 127);
    float4 r;
    r.x = fmaxf(0.f, sc[cb + 0] * v.x + sh[cb + 0]);
    r.y = fmaxf(0.f, sc[cb + 1] * v.y + sh[cb + 1]);
    r.z = fmaxf(0.f, sc[cb + 2] * v.z + sh[cb + 2]);
    r.w = fmaxf(0.f, sc[cb + 3] * v.w + sh[cb + 3]);
    ((float4*)out)[e4] = r;
}

// ---------------------------------------------------------------------------
extern "C" void kernel_launch(void* const* d_in, const int* in_sizes, int n_in,
                              void* d_out, int out_size, void* d_ws, size_t ws_size,
                              hipStream_t stream)
{
    const float* xyz    = (const float*)d_in[0];
    const float* points = (const float*)d_in[1];
    const float* lc     = (const float*)d_in[2];
    const int*   nl     = (const int*)d_in[3];
    // d_in[4] parameter_list: unused
    const int*   didx   = (const int*)d_in[5];
    const float* W1     = (const float*)d_in[6];
    const float* b1     = (const float*)d_in[7];
    const float* g1     = (const float*)d_in[8];
    const float* be1    = (const float*)d_in[9];
    const float* W2     = (const float*)d_in[10];
    const float* b2     = (const float*)d_in[11];
    const float* g2     = (const float*)d_in[12];
    const float* be2    = (const float*)d_in[13];

    float* out = (float*)d_out;
    char*  ws  = (char*)d_ws;

    // workspace layout (bytes)
    unsigned short* feat = (unsigned short*)ws;                   // 20,971,520 B
    float*          x1   = (float*)(ws + 20971520);               // 16,777,216 B
    unsigned short* W1t  = (unsigned short*)(ws + 37748736);      //     81,920 B
    unsigned short* W2t  = (unsigned short*)(ws + 37830656);      //     32,768 B
    float*          st   = (float*)(ws + 37863424);               //      2,048 B
    float*          y    = (float*)ws;                            // reuse feat region

    prep_kernel<<<224, 256, 0, stream>>>(W1, W2, W1t, W2t, st);
    gather_kernel<<<M_ROWS / 4, 256, 0, stream>>>(xyz, points, lc, nl, didx, feat, out);
    gemm1_mfma<<<M_ROWS / 64, 256, 0, stream>>>(feat, W1t, b1, x1, st, st + 128);
    gemm2_mfma<<<M_ROWS / 64, 256, 0, stream>>>(x1, st, st + 128, g1, be1,
                                                W2t, b2, y, st + 256, st + 384);
    out_kernel<<<(M_ROWS * C_OUT) / (256 * 4), 256, 0, stream>>>(
        y, st + 256, st + 384, g2, be2, out + (size_t)M_ROWS * 3);
}

// Round 5
// 219.684 us; speedup vs baseline: 1.1883x; 1.0332x over previous
//
#include <hip/hip_runtime.h>
#include <hip/hip_bf16.h>
#include <math.h>

// Problem constants (from reference)
#define B_SZ     16
#define N_PTS    8192
#define NPOINT   2048
#define KNBR     32
#define D_FEAT   61
#define C_IN     64            // D_FEAT + 3
#define P_BINS   5
#define C_OUT    128
#define M_ROWS   (B_SZ * NPOINT)          // 32768
#define K1       (C_IN * P_BINS)          // 320
#define EPSV     1e-5f

typedef __attribute__((ext_vector_type(8))) short bf16x8;
typedef __attribute__((ext_vector_type(4))) float f32x4;

__device__ __forceinline__ unsigned short f2bf_rne(float v) {
    unsigned u = __float_as_uint(v);
    u += 0x7fffu + ((u >> 16) & 1u);
    return (unsigned short)(u >> 16);
}
__device__ __forceinline__ float bf2f(unsigned short v) {
    return __uint_as_float(((unsigned)v) << 16);
}

// ---------------------------------------------------------------------------
// Prep: (a) blocks [0,32768): build pts[B][N][64] bf16 = concat(points,xyz),
//       batch->XCD pinned so gather reads hit the same L2.
//       (b) blocks [32768,32992): W1->W1t[128][320] bf16, W2->W2t[128][128]
//       bf16, zero 512-float stats.
// ---------------------------------------------------------------------------
__global__ __launch_bounds__(256) void prep_kernel(
    const float* __restrict__ points, const float* __restrict__ xyz,
    const float* __restrict__ W1, const float* __restrict__ W2,
    unsigned short* __restrict__ ptsb, unsigned short* __restrict__ W1t,
    unsigned short* __restrict__ W2t, float* __restrict__ st)
{
    const int blk = blockIdx.x;
    const int tid = threadIdx.x;
    if (blk < 32768) {
        const int xcd  = blk & 7;
        const int slot = blk >> 3;                    // 0..4095
        const int b    = 2 * xcd + (slot >> 11);      // batch -> XCD b/2
        const int rin  = (slot & 2047) * 4 + (tid >> 6);
        const int row  = b * N_PTS + rin;
        const int c    = tid & 63;
        float v;
        if (c < D_FEAT) v = points[(size_t)row * D_FEAT + c];
        else            v = xyz[(size_t)row * 3 + (c - D_FEAT)];
        ptsb[((size_t)row << 6) | c] = f2bf_rne(v);
    } else {
        const int gid = (blk - 32768) * 256 + tid;
        if (gid < 512) st[gid] = 0.f;
        if (gid < K1 * C_OUT) {
            int k = gid >> 7, n = gid & 127;
            W1t[(size_t)n * K1 + k] = f2bf_rne(W1[gid]);
        } else {
            int i = gid - K1 * C_OUT;
            if (i < C_OUT * C_OUT) {
                int k = i >> 7, n = i & 127;
                W2t[(size_t)n * C_OUT + k] = f2bf_rne(W2[i]);
            }
        }
    }
}

// ---------------------------------------------------------------------------
// Gather: 4 points/block (wave per point), lane = channel (64).
// Loop 1 (unrolled): issue 32 independent row loads (SGPR base via readlane).
// Loop 2 (unrolled): accumulate with wave-uniform scalar if-chain on bin.
// ---------------------------------------------------------------------------
__global__ __launch_bounds__(256) void gather_kernel(
    const unsigned short* __restrict__ ptsb, const float* __restrict__ xyz,
    const float* __restrict__ lc, const int* __restrict__ nl,
    const int* __restrict__ didx, unsigned short* __restrict__ feat,
    float* __restrict__ newxyz)
{
    const int g    = blockIdx.x;             // 0..8191
    const int xcd  = g & 7;
    const int slot = g >> 3;                 // 0..1023
    const int b    = 2 * xcd + (slot >> 9);
    const int m    = (slot & 511) * 4 + (threadIdx.x >> 6);
    const int bid  = b * NPOINT + m;
    const int lane = threadIdx.x & 63;
    const int k    = lane & 31;

    // bins + neighbor indices (lanes 32-63 mirror lanes 0-31; readlane uses 0-31)
    const size_t nbase = (size_t)bid * KNBR;
    const float x = lc[(nbase + k) * 3 + 0];
    const float y = lc[(nbase + k) * 3 + 1];
    const float d = fminf(sqrtf(x * x + y * y) * (1.0f / 1.5f), 0.99f);
    int bin = (int)(d * 5.0f);
    bin = bin > 4 ? 4 : (bin < 0 ? 0 : bin);
    const int n = nl[nbase + k];

    if (lane >= 32 && lane < 35) {
        const int di = didx[bid];
        const int j = lane - 32;
        newxyz[(size_t)bid * 3 + j] = xyz[((size_t)b * N_PTS + di) * 3 + j];
    }

    const unsigned short* __restrict__ pb = ptsb + (((size_t)b * N_PTS) << 6);

    // loop 1: all 32 loads in flight
    unsigned short vv[32];
    #pragma unroll
    for (int kk = 0; kk < 32; ++kk) {
        const int nk = __builtin_amdgcn_readlane(n, kk);
        vv[kk] = pb[((size_t)nk << 6) | lane];
    }

    // loop 2: scalar-branch accumulation
    float a0 = 0.f, a1 = 0.f, a2 = 0.f, a3 = 0.f, a4 = 0.f;
    #pragma unroll
    for (int kk = 0; kk < 32; ++kk) {
        const int bk = __builtin_amdgcn_readlane(bin, kk);
        const float v = bf2f(vv[kk]);
        if      (bk == 0) a0 += v;
        else if (bk == 1) a1 += v;
        else if (bk == 2) a2 += v;
        else if (bk == 3) a3 += v;
        else              a4 += v;
    }

    unsigned short* fr = feat + (size_t)bid * K1;
    fr[lane]       = f2bf_rne(a0);
    fr[64 + lane]  = f2bf_rne(a1);
    fr[128 + lane] = f2bf_rne(a2);
    fr[192 + lane] = f2bf_rne(a3);
    fr[256 + lane] = f2bf_rne(a4);
}

// ---------------------------------------------------------------------------
// GEMM1 (MFMA bf16, no LDS tiles): x1 = feat @ W1 + b1 -> bf16 out (stats f32).
// 4 waves/block, wave = 16 rows x 128 cols. Fused per-channel sum/sumsq.
// Fragment (16x16x32): A/B: k=(lane>>4)*8+j; D: col=lane&15,row=(lane>>4)*4+i.
// Batch->XCD pinned (feat rows were produced on this XCD).
// ---------------------------------------------------------------------------
__global__ __launch_bounds__(256) void gemm1_mfma(
    const unsigned short* __restrict__ A, const unsigned short* __restrict__ Wt,
    const float* __restrict__ bias, unsigned short* __restrict__ out,
    float* __restrict__ sum, float* __restrict__ sumsq)
{
    const int g    = blockIdx.x;             // 0..511
    const int xcd  = g & 7;
    const int slot = g >> 3;                 // 0..63
    const int bb_  = 2 * xcd + (slot >> 5);
    const int r0b  = (bb_ * 32 + (slot & 31)) * 64;

    const int tid  = threadIdx.x;
    const int wave = tid >> 6, lane = tid & 63;
    const int lm = lane & 15, kg = lane >> 4;
    const int r0 = r0b + wave * 16;

    f32x4 acc[8] = {};
    const unsigned short* arow = A + (size_t)(r0 + lm) * K1 + kg * 8;

    #pragma unroll
    for (int kb = 0; kb < K1; kb += 32) {
        bf16x8 a = *(const bf16x8*)(arow + kb);
        #pragma unroll
        for (int nf = 0; nf < 8; ++nf) {
            bf16x8 bfr = *(const bf16x8*)(Wt + (size_t)(nf * 16 + lm) * K1 + kb + kg * 8);
            acc[nf] = __builtin_amdgcn_mfma_f32_16x16x32_bf16(a, bfr, acc[nf], 0, 0, 0);
        }
    }

    __shared__ float s_s[4][128], s_q[4][128];
    const int orow = r0 + kg * 4;
    #pragma unroll
    for (int nf = 0; nf < 8; ++nf) {
        const int col = nf * 16 + lm;
        const float bb = bias[col];
        float ls = 0.f, lq = 0.f;
        #pragma unroll
        for (int i = 0; i < 4; ++i) {
            float v = acc[nf][i] + bb;
            out[(size_t)(orow + i) * C_OUT + col] = f2bf_rne(v);
            ls += v; lq += v * v;
        }
        ls += __shfl_xor(ls, 16); ls += __shfl_xor(ls, 32);
        lq += __shfl_xor(lq, 16); lq += __shfl_xor(lq, 32);
        if (kg == 0) { s_s[wave][col] = ls; s_q[wave][col] = lq; }
    }
    __syncthreads();
    if (tid < 128) {
        float ts = s_s[0][tid] + s_s[1][tid] + s_s[2][tid] + s_s[3][tid];
        float tq = s_q[0][tid] + s_q[1][tid] + s_q[2][tid] + s_q[3][tid];
        atomicAdd(&sum[tid], ts);
        atomicAdd(&sumsq[tid], tq);
    }
}

// ---------------------------------------------------------------------------
// GEMM2 (MFMA bf16): y = relu(BN1(x1)) @ W2 + b2 -> bf16 out, stats for BN2.
// ---------------------------------------------------------------------------
__global__ __launch_bounds__(256) void gemm2_mfma(
    const unsigned short* __restrict__ X,
    const float* __restrict__ sum1, const float* __restrict__ sq1,
    const float* __restrict__ g1, const float* __restrict__ be1,
    const unsigned short* __restrict__ Wt, const float* __restrict__ bias,
    unsigned short* __restrict__ out, float* __restrict__ sum,
    float* __restrict__ sumsq)
{
    __shared__ float sc[128], sh[128];
    __shared__ float s_s[4][128], s_q[4][128];
    const int tid = threadIdx.x;
    if (tid < 128) {
        float mu  = sum1[tid] * (1.0f / (float)M_ROWS);
        float var = sq1[tid] * (1.0f / (float)M_ROWS) - mu * mu;
        float iv  = 1.0f / sqrtf(var + EPSV);
        float s   = g1[tid] * iv;
        sc[tid] = s;
        sh[tid] = be1[tid] - mu * s;
    }
    __syncthreads();

    const int g    = blockIdx.x;
    const int xcd  = g & 7;
    const int slot = g >> 3;
    const int bb_  = 2 * xcd + (slot >> 5);
    const int r0   = (bb_ * 32 + (slot & 31)) * 64 + (tid >> 6) * 16;

    const int wave = tid >> 6, lane = tid & 63;
    const int lm = lane & 15, kg = lane >> 4;
    const unsigned short* xrow = X + (size_t)(r0 + lm) * C_OUT;

    f32x4 acc[8] = {};

    #pragma unroll
    for (int kb = 0; kb < C_OUT; kb += 32) {
        const int k0 = kb + kg * 8;
        bf16x8 xr = *(const bf16x8*)(xrow + k0);
        bf16x8 a;
        #pragma unroll
        for (int j = 0; j < 8; ++j) {
            float xv = bf2f((unsigned short)xr[j]);
            float v  = fmaxf(0.f, sc[k0 + j] * xv + sh[k0 + j]);
            a[j] = (short)f2bf_rne(v);
        }
        #pragma unroll
        for (int nf = 0; nf < 8; ++nf) {
            bf16x8 bfr = *(const bf16x8*)(Wt + (size_t)(nf * 16 + lm) * C_OUT + k0);
            acc[nf] = __builtin_amdgcn_mfma_f32_16x16x32_bf16(a, bfr, acc[nf], 0, 0, 0);
        }
    }

    const int orow = r0 + kg * 4;
    #pragma unroll
    for (int nf = 0; nf < 8; ++nf) {
        const int col = nf * 16 + lm;
        const float bb = bias[col];
        float ls = 0.f, lq = 0.f;
        #pragma unroll
        for (int i = 0; i < 4; ++i) {
            float v = acc[nf][i] + bb;
            out[(size_t)(orow + i) * C_OUT + col] = f2bf_rne(v);
            ls += v; lq += v * v;
        }
        ls += __shfl_xor(ls, 16); ls += __shfl_xor(ls, 32);
        lq += __shfl_xor(lq, 16); lq += __shfl_xor(lq, 32);
        if (kg == 0) { s_s[wave][col] = ls; s_q[wave][col] = lq; }
    }
    __syncthreads();
    if (tid < 128) {
        float ts = s_s[0][tid] + s_s[1][tid] + s_s[2][tid] + s_s[3][tid];
        float tq = s_q[0][tid] + s_q[1][tid] + s_q[2][tid] + s_q[3][tid];
        atomicAdd(&sum[tid], ts);
        atomicAdd(&sumsq[tid], tq);
    }
}

// ---------------------------------------------------------------------------
// Final: new_points = relu(BN2(y)), y in bf16, out f32.
// ---------------------------------------------------------------------------
__global__ __launch_bounds__(256) void out_kernel(
    const unsigned short* __restrict__ Y,
    const float* __restrict__ sum2, const float* __restrict__ sq2,
    const float* __restrict__ g2, const float* __restrict__ be2,
    float* __restrict__ out)
{
    __shared__ float sc[128], sh[128];
    const int tid = threadIdx.x;
    if (tid < 128) {
        float mu  = sum2[tid] * (1.0f / (float)M_ROWS);
        float var = sq2[tid] * (1.0f / (float)M_ROWS) - mu * mu;
        float iv  = 1.0f / sqrtf(var + EPSV);
        float s   = g2[tid] * iv;
        sc[tid] = s;
        sh[tid] = be2[tid] - mu * s;
    }
    __syncthreads();

    const size_t e8 = (size_t)blockIdx.x * 256 + tid;   // ushort8 index
    bf16x8 v = ((const bf16x8*)Y)[e8];
    const int cb = (int)((e8 * 8) & 127);
    float4 r0, r1;
    r0.x = fmaxf(0.f, sc[cb + 0] * bf2f((unsigned short)v[0]) + sh[cb + 0]);
    r0.y = fmaxf(0.f, sc[cb + 1] * bf2f((unsigned short)v[1]) + sh[cb + 1]);
    r0.z = fmaxf(0.f, sc[cb + 2] * bf2f((unsigned short)v[2]) + sh[cb + 2]);
    r0.w = fmaxf(0.f, sc[cb + 3] * bf2f((unsigned short)v[3]) + sh[cb + 3]);
    r1.x = fmaxf(0.f, sc[cb + 4] * bf2f((unsigned short)v[4]) + sh[cb + 4]);
    r1.y = fmaxf(0.f, sc[cb + 5] * bf2f((unsigned short)v[5]) + sh[cb + 5]);
    r1.z = fmaxf(0.f, sc[cb + 6] * bf2f((unsigned short)v[6]) + sh[cb + 6]);
    r1.w = fmaxf(0.f, sc[cb + 7] * bf2f((unsigned short)v[7]) + sh[cb + 7]);
    ((float4*)out)[e8 * 2]     = r0;
    ((float4*)out)[e8 * 2 + 1] = r1;
}

// ---------------------------------------------------------------------------
extern "C" void kernel_launch(void* const* d_in, const int* in_sizes, int n_in,
                              void* d_out, int out_size, void* d_ws, size_t ws_size,
                              hipStream_t stream)
{
    const float* xyz    = (const float*)d_in[0];
    const float* points = (const float*)d_in[1];
    const float* lc     = (const float*)d_in[2];
    const int*   nl     = (const int*)d_in[3];
    // d_in[4] parameter_list: unused
    const int*   didx   = (const int*)d_in[5];
    const float* W1     = (const float*)d_in[6];
    const float* b1     = (const float*)d_in[7];
    const float* g1     = (const float*)d_in[8];
    const float* be1    = (const float*)d_in[9];
    const float* W2     = (const float*)d_in[10];
    const float* b2     = (const float*)d_in[11];
    const float* g2     = (const float*)d_in[12];
    const float* be2    = (const float*)d_in[13];

    float* out = (float*)d_out;
    char*  ws  = (char*)d_ws;

    // workspace layout (bytes), total 37,865,472 (same footprint as round-4):
    // region A [0, 16.78MB): ptsb (prep/gather), then x1b + yb (dead ptsb)
    // region B [16.78MB, 37.75MB): feat
    // region C: W1t, W2t, stats
    unsigned short* ptsb = (unsigned short*)ws;                   // 16,777,216 B
    unsigned short* x1b  = (unsigned short*)ws;                   //  8,388,608 B
    unsigned short* yb   = (unsigned short*)(ws + 8388608);       //  8,388,608 B
    unsigned short* feat = (unsigned short*)(ws + 16777216);      // 20,971,520 B
    unsigned short* W1t  = (unsigned short*)(ws + 37748736);      //     81,920 B
    unsigned short* W2t  = (unsigned short*)(ws + 37830656);      //     32,768 B
    float*          st   = (float*)(ws + 37863424);               //      2,048 B

    prep_kernel<<<32768 + 224, 256, 0, stream>>>(points, xyz, W1, W2,
                                                 ptsb, W1t, W2t, st);
    gather_kernel<<<M_ROWS / 4, 256, 0, stream>>>(ptsb, xyz, lc, nl, didx, feat, out);
    gemm1_mfma<<<M_ROWS / 64, 256, 0, stream>>>(feat, W1t, b1, x1b, st, st + 128);
    gemm2_mfma<<<M_ROWS / 64, 256, 0, stream>>>(x1b, st, st + 128, g1, be1,
                                                W2t, b2, yb, st + 256, st + 384);
    out_kernel<<<(M_ROWS * C_OUT) / (256 * 8), 256, 0, stream>>>(
        yb, st + 256, st + 384, g2, be2, out + (size_t)M_ROWS * 3);
}

// Round 7
// 200.069 us; speedup vs baseline: 1.3048x; 1.0980x over previous
//
#include <hip/hip_runtime.h>
#include <hip/hip_bf16.h>
#include <math.h>

// Problem constants (from reference)
#define B_SZ     16
#define N_PTS    8192
#define NPOINT   2048
#define KNBR     32
#define D_FEAT   61
#define C_IN     64            // D_FEAT + 3
#define P_BINS   5
#define C_OUT    128
#define M_ROWS   (B_SZ * NPOINT)          // 32768
#define K1       (C_IN * P_BINS)          // 320
#define EPSV     1e-5f

typedef __attribute__((ext_vector_type(8))) short bf16x8;
typedef __attribute__((ext_vector_type(4))) float f32x4;

__device__ __forceinline__ unsigned short f2bf_rne(float v) {
    unsigned u = __float_as_uint(v);
    u += 0x7fffu + ((u >> 16) & 1u);
    return (unsigned short)(u >> 16);
}
__device__ __forceinline__ float bf2f(unsigned short v) {
    return __uint_as_float(((unsigned)v) << 16);
}

// Fragment-major index helpers (16x16x32 MFMA).
// A-side element (row m, ch c), K-chunks KCH = K/32:
//   idx = ((m>>4)*KCH + (c>>5))*512 + (((c>>3)&3)*16 + (m&15))*8 + (c&7)
// B-side element (col n, ch c):
//   idx = ((c>>5)*8 + (n>>4))*512 + (((c>>3)&3)*16 + (n&15))*8 + (c&7)
__device__ __forceinline__ size_t fragB_idx(int n, int c) {
    return ((size_t)((c >> 5) * 8 + (n >> 4)) << 9) +
           ((((c >> 3) & 3) * 16 + (n & 15)) << 3) + (c & 7);
}

// ---------------------------------------------------------------------------
// Prep: (a) blocks [0,32768): build pts[B][N][64] bf16 = concat(points,xyz),
//       batch->XCD pinned. (b) blocks [32768,32992): W1,W2 -> fragment-major
//       bf16 (W1f[10][8][64][8], W2f[4][8][64][8]); zero 512-float stats.
// ---------------------------------------------------------------------------
__global__ __launch_bounds__(256) void prep_kernel(
    const float* __restrict__ points, const float* __restrict__ xyz,
    const float* __restrict__ W1, const float* __restrict__ W2,
    unsigned short* __restrict__ ptsb, unsigned short* __restrict__ W1f,
    unsigned short* __restrict__ W2f, float* __restrict__ st)
{
    const int blk = blockIdx.x;
    const int tid = threadIdx.x;
    if (blk < 32768) {
        const int xcd  = blk & 7;
        const int slot = blk >> 3;                    // 0..4095
        const int b    = 2 * xcd + (slot >> 11);      // batch -> XCD b/2
        const int rin  = (slot & 2047) * 4 + (tid >> 6);
        const int row  = b * N_PTS + rin;
        const int c    = tid & 63;
        float v;
        if (c < D_FEAT) v = points[(size_t)row * D_FEAT + c];
        else            v = xyz[(size_t)row * 3 + (c - D_FEAT)];
        ptsb[((size_t)row << 6) | c] = f2bf_rne(v);
    } else {
        const int gid = (blk - 32768) * 256 + tid;    // 0..57343
        if (gid < 512) st[gid] = 0.f;
        if (gid < K1 * C_OUT) {                       // 40960
            int c = gid >> 7, n = gid & 127;
            W1f[fragB_idx(n, c)] = f2bf_rne(W1[gid]);
        } else {
            int i = gid - K1 * C_OUT;                 // < 16384
            int c = i >> 7, n = i & 127;
            W2f[fragB_idx(n, c)] = f2bf_rne(W2[i]);
        }
    }
}

// ---------------------------------------------------------------------------
// Gather: 1 point per wave (4/block). Ballot counting-sort by bin, stage the
// 32 sorted rows into LDS with 4 coalesced dwordx4 loads, then lane=channel
// prefix accumulation (1 ds_read_u16 + 1 add per element); bin sums are
// differences of prefixes captured at wave-uniform run boundaries.
// Writes feat in A-fragment-major order (KCH=10) + new_xyz.
// ---------------------------------------------------------------------------
__global__ __launch_bounds__(256) void gather_kernel(
    const unsigned short* __restrict__ ptsb, const float* __restrict__ xyz,
    const float* __restrict__ lc, const int* __restrict__ nl,
    const int* __restrict__ didx, unsigned short* __restrict__ featf,
    float* __restrict__ newxyz)
{
    const int g    = blockIdx.x;             // 0..8191
    const int xcd  = g & 7;
    const int slot = g >> 3;                 // 0..1023
    const int b    = 2 * xcd + (slot >> 9);
    const int wave = threadIdx.x >> 6;
    const int m    = (slot & 511) * 4 + wave;
    const int bid  = b * NPOINT + m;
    const int lane = threadIdx.x & 63;
    const int k    = lane & 31;

    __shared__ int s_srt[4][32];
    __shared__ __align__(16) unsigned short s_stage[4][32][64];

    // bins + neighbor indices (lanes 32-63 mirror lanes 0-31)
    const size_t nbase = (size_t)bid * KNBR;
    const float x = lc[(nbase + k) * 3 + 0];
    const float y = lc[(nbase + k) * 3 + 1];
    const float d = fminf(sqrtf(x * x + y * y) * (1.0f / 1.5f), 0.99f);
    int bin = (int)(d * 5.0f);
    bin = bin > 4 ? 4 : (bin < 0 ? 0 : bin);
    const int n = nl[nbase + k];

    // ballot counting sort (low 32 bits; lanes 0-31 authoritative)
    unsigned m0 = (unsigned)__ballot(bin == 0);
    unsigned m1 = (unsigned)__ballot(bin == 1);
    unsigned m2 = (unsigned)__ballot(bin == 2);
    unsigned m3 = (unsigned)__ballot(bin == 3);
    unsigned m4 = (unsigned)__ballot(bin == 4);
    const int c0n = __popc(m0), c1n = __popc(m1), c2n = __popc(m2), c3n = __popc(m3);
    const int e0 = c0n, e1 = e0 + c1n, e2 = e1 + c2n, e3 = e2 + c3n;

    int start = (bin > 0 ? c0n : 0) + (bin > 1 ? c1n : 0) +
                (bin > 2 ? c2n : 0) + (bin > 3 ? c3n : 0);
    unsigned mymask = m0;
    mymask = bin == 1 ? m1 : mymask;
    mymask = bin == 2 ? m2 : mymask;
    mymask = bin == 3 ? m3 : mymask;
    mymask = bin == 4 ? m4 : mymask;
    const int pos = start + __popc(mymask & ((1u << k) - 1u));

    if (lane < 32) s_srt[wave][pos] = n;
    if (lane >= 32 && lane < 35) {
        const int di = didx[bid];
        const int j = lane - 32;
        newxyz[(size_t)bid * 3 + j] = xyz[((size_t)b * N_PTS + di) * 3 + j];
    }

    // stage 32 sorted rows: lane (r = lane>>3, j7 = lane&7), 16B chunks
    const unsigned short* __restrict__ pb = ptsb + (((size_t)b * N_PTS) << 6);
    const int r = lane >> 3, j7 = lane & 7;
    #pragma unroll
    for (int g4 = 0; g4 < 4; ++g4) {
        const int nr = s_srt[wave][g4 * 8 + r];
        bf16x8 row = *(const bf16x8*)(pb + ((size_t)nr << 6) + j7 * 8);
        *(bf16x8*)&s_stage[wave][g4 * 8 + r][j7 * 8] = row;
    }

    // prefix accumulation, lane = channel
    float acc = 0.f, pre0 = 0.f, pre1 = 0.f, pre2 = 0.f, pre3 = 0.f;
    #pragma unroll
    for (int kk = 0; kk < 32; ++kk) {
        acc += bf2f(s_stage[wave][kk][lane]);
        const int kp = kk + 1;
        if (kp == e0) pre0 = acc;
        if (kp == e1) pre1 = acc;
        if (kp == e2) pre2 = acc;
        if (kp == e3) pre3 = acc;
    }
    float vals[5];
    vals[0] = pre0;
    vals[1] = pre1 - pre0;
    vals[2] = pre2 - pre1;
    vals[3] = pre3 - pre2;
    vals[4] = acc - pre3;

    // write feat in A-fragment-major order (KCH = 10)
    const int t = bid >> 4, lm = bid & 15;
    const int kgl = (lane >> 3) & 3, jl = lane & 7;
    #pragma unroll
    for (int bb = 0; bb < 5; ++bb) {
        const int kb = bb * 2 + (lane >> 5);
        const size_t idx = (((size_t)(t * 10 + kb)) << 9) +
                           ((kgl * 16 + lm) << 3) + jl;
        featf[idx] = f2bf_rne(vals[bb]);
    }
}

// ---------------------------------------------------------------------------
// GEMM1 (MFMA bf16, fragment-major A and B): x1 = feat @ W1 + b1.
// All operand loads are contiguous 1KB/wave. Writes x1 in A-frag order
// (KCH=4) for gemm2. Fused per-channel sum/sumsq.
// ---------------------------------------------------------------------------
__global__ __launch_bounds__(256) void gemm1_mfma(
    const unsigned short* __restrict__ Af, const unsigned short* __restrict__ Wf,
    const float* __restrict__ bias, unsigned short* __restrict__ outf,
    float* __restrict__ sum, float* __restrict__ sumsq)
{
    const int g    = blockIdx.x;             // 0..511
    const int xcd  = g & 7;
    const int slot = g >> 3;                 // 0..63
    const int bb_  = 2 * xcd + (slot >> 5);
    const int tile = (bb_ * 32 + (slot & 31)) * 4 + (threadIdx.x >> 6);

    const int tid  = threadIdx.x;
    const int wave = tid >> 6, lane = tid & 63;
    const int lm = lane & 15, kg = lane >> 4;

    f32x4 acc[8] = {};
    #pragma unroll
    for (int kb = 0; kb < 10; ++kb) {
        bf16x8 a = *(const bf16x8*)(Af + (((size_t)(tile * 10 + kb)) << 9) + lane * 8);
        #pragma unroll
        for (int nf = 0; nf < 8; ++nf) {
            bf16x8 bfr = *(const bf16x8*)(Wf + (((size_t)(kb * 8 + nf)) << 9) + lane * 8);
            acc[nf] = __builtin_amdgcn_mfma_f32_16x16x32_bf16(a, bfr, acc[nf], 0, 0, 0);
        }
    }

    __shared__ float s_s[4][128], s_q[4][128];
    #pragma unroll
    for (int nf = 0; nf < 8; ++nf) {
        const int col = nf * 16 + lm;
        const float bb = bias[col];
        float ls = 0.f, lq = 0.f;
        #pragma unroll
        for (int i = 0; i < 4; ++i) {
            float v = acc[nf][i] + bb;
            // x1 frag store: row r = tile*16 + kg*4 + i, ch c = col (KCH=4)
            const size_t idx = (((size_t)(tile * 4 + (col >> 5))) << 9) +
                               ((((col >> 3) & 3) * 16 + kg * 4 + i) << 3) + (col & 7);
            outf[idx] = f2bf_rne(v);
            ls += v; lq += v * v;
        }
        ls += __shfl_xor(ls, 16); ls += __shfl_xor(ls, 32);
        lq += __shfl_xor(lq, 16); lq += __shfl_xor(lq, 32);
        if (kg == 0) { s_s[wave][col] = ls; s_q[wave][col] = lq; }
    }
    __syncthreads();
    if (tid < 128) {
        float ts = s_s[0][tid] + s_s[1][tid] + s_s[2][tid] + s_s[3][tid];
        float tq = s_q[0][tid] + s_q[1][tid] + s_q[2][tid] + s_q[3][tid];
        atomicAdd(&sum[tid], ts);
        atomicAdd(&sumsq[tid], tq);
    }
}

// ---------------------------------------------------------------------------
// GEMM2 (MFMA bf16): y = relu(BN1(x1)) @ W2 + b2, BN1 fused into A-frag load.
// A from x1 frag-major (KCH=4), B from W2 frag-major. y row-major bf16.
// ---------------------------------------------------------------------------
__global__ __launch_bounds__(256) void gemm2_mfma(
    const unsigned short* __restrict__ Xf,
    const float* __restrict__ sum1, const float* __restrict__ sq1,
    const float* __restrict__ g1, const float* __restrict__ be1,
    const unsigned short* __restrict__ Wf, const float* __restrict__ bias,
    unsigned short* __restrict__ out, float* __restrict__ sum,
    float* __restrict__ sumsq)
{
    __shared__ float sc[128], sh[128];
    __shared__ float s_s[4][128], s_q[4][128];
    const int tid = threadIdx.x;
    if (tid < 128) {
        float mu  = sum1[tid] * (1.0f / (float)M_ROWS);
        float var = sq1[tid] * (1.0f / (float)M_ROWS) - mu * mu;
        float iv  = 1.0f / sqrtf(var + EPSV);
        float s   = g1[tid] * iv;
        sc[tid] = s;
        sh[tid] = be1[tid] - mu * s;
    }
    __syncthreads();

    const int g    = blockIdx.x;
    const int xcd  = g & 7;
    const int slot = g >> 3;
    const int bb_  = 2 * xcd + (slot >> 5);
    const int tile = (bb_ * 32 + (slot & 31)) * 4 + (tid >> 6);

    const int wave = tid >> 6, lane = tid & 63;
    const int lm = lane & 15, kg = lane >> 4;

    f32x4 acc[8] = {};
    #pragma unroll
    for (int kb = 0; kb < 4; ++kb) {
        const int c0 = kb * 32 + kg * 8;
        bf16x8 xr = *(const bf16x8*)(Xf + (((size_t)(tile * 4 + kb)) << 9) + lane * 8);
        f32x4 s0 = *(const f32x4*)&sc[c0];
        f32x4 s1 = *(const f32x4*)&sc[c0 + 4];
        f32x4 h0 = *(const f32x4*)&sh[c0];
        f32x4 h1 = *(const f32x4*)&sh[c0 + 4];
        bf16x8 a;
        #pragma unroll
        for (int j = 0; j < 4; ++j) {
            a[j]     = (short)f2bf_rne(fmaxf(0.f, s0[j] * bf2f((unsigned short)xr[j]) + h0[j]));
            a[4 + j] = (short)f2bf_rne(fmaxf(0.f, s1[j] * bf2f((unsigned short)xr[4 + j]) + h1[j]));
        }
        #pragma unroll
        for (int nf = 0; nf < 8; ++nf) {
            bf16x8 bfr = *(const bf16x8*)(Wf + (((size_t)(kb * 8 + nf)) << 9) + lane * 8);
            acc[nf] = __builtin_amdgcn_mfma_f32_16x16x32_bf16(a, bfr, acc[nf], 0, 0, 0);
        }
    }

    const int orow = tile * 16 + kg * 4;
    #pragma unroll
    for (int nf = 0; nf < 8; ++nf) {
        const int col = nf * 16 + lm;
        const float bb = bias[col];
        float ls = 0.f, lq = 0.f;
        #pragma unroll
        for (int i = 0; i < 4; ++i) {
            float v = acc[nf][i] + bb;
            out[(size_t)(orow + i) * C_OUT + col] = f2bf_rne(v);
            ls += v; lq += v * v;
        }
        ls += __shfl_xor(ls, 16); ls += __shfl_xor(ls, 32);
        lq += __shfl_xor(lq, 16); lq += __shfl_xor(lq, 32);
        if (kg == 0) { s_s[wave][col] = ls; s_q[wave][col] = lq; }
    }
    __syncthreads();
    if (tid < 128) {
        float ts = s_s[0][tid] + s_s[1][tid] + s_s[2][tid] + s_s[3][tid];
        float tq = s_q[0][tid] + s_q[1][tid] + s_q[2][tid] + s_q[3][tid];
        atomicAdd(&sum[tid], ts);
        atomicAdd(&sumsq[tid], tq);
    }
}

// ---------------------------------------------------------------------------
// Final: new_points = relu(BN2(y)), y bf16 row-major, out f32.
// ---------------------------------------------------------------------------
__global__ __launch_bounds__(256) void out_kernel(
    const unsigned short* __restrict__ Y,
    const float* __restrict__ sum2, const float* __restrict__ sq2,
    const float* __restrict__ g2, const float* __restrict__ be2,
    float* __restrict__ out)
{
    __shared__ float sc[128], sh[128];
    const int tid = threadIdx.x;
    if (tid < 128) {
        float mu  = sum2[tid] * (1.0f / (float)M_ROWS);
        float var = sq2[tid] * (1.0f / (float)M_ROWS) - mu * mu;
        float iv  = 1.0f / sqrtf(var + EPSV);
        float s   = g2[tid] * iv;
        sc[tid] = s;
        sh[tid] = be2[tid] - mu * s;
    }
    __syncthreads();

    const size_t e8 = (size_t)blockIdx.x * 256 + tid;   // ushort8 index
    bf16x8 v = ((const bf16x8*)Y)[e8];
    const int cb = (int)((e8 * 8) & 127);
    float4 r0, r1;
    r0.x = fmaxf(0.f, sc[cb + 0] * bf2f((unsigned short)v[0]) + sh[cb + 0]);
    r0.y = fmaxf(0.f, sc[cb + 1] * bf2f((unsigned short)v[1]) + sh[cb + 1]);
    r0.z = fmaxf(0.f, sc[cb + 2] * bf2f((unsigned short)v[2]) + sh[cb + 2]);
    r0.w = fmaxf(0.f, sc[cb + 3] * bf2f((unsigned short)v[3]) + sh[cb + 3]);
    r1.x = fmaxf(0.f, sc[cb + 4] * bf2f((unsigned short)v[4]) + sh[cb + 4]);
    r1.y = fmaxf(0.f, sc[cb + 5] * bf2f((unsigned short)v[5]) + sh[cb + 5]);
    r1.z = fmaxf(0.f, sc[cb + 6] * bf2f((unsigned short)v[6]) + sh[cb + 6]);
    r1.w = fmaxf(0.f, sc[cb + 7] * bf2f((unsigned short)v[7]) + sh[cb + 7]);
    ((float4*)out)[e8 * 2]     = r0;
    ((float4*)out)[e8 * 2 + 1] = r1;
}

// ---------------------------------------------------------------------------
extern "C" void kernel_launch(void* const* d_in, const int* in_sizes, int n_in,
                              void* d_out, int out_size, void* d_ws, size_t ws_size,
                              hipStream_t stream)
{
    const float* xyz    = (const float*)d_in[0];
    const float* points = (const float*)d_in[1];
    const float* lc     = (const float*)d_in[2];
    const int*   nl     = (const int*)d_in[3];
    // d_in[4] parameter_list: unused
    const int*   didx   = (const int*)d_in[5];
    const float* W1     = (const float*)d_in[6];
    const float* b1     = (const float*)d_in[7];
    const float* g1     = (const float*)d_in[8];
    const float* be1    = (const float*)d_in[9];
    const float* W2     = (const float*)d_in[10];
    const float* b2     = (const float*)d_in[11];
    const float* g2     = (const float*)d_in[12];
    const float* be2    = (const float*)d_in[13];

    float* out = (float*)d_out;
    char*  ws  = (char*)d_ws;

    // workspace layout (bytes), total 37,865,472:
    // region A [0, 16.78MB): ptsb (prep/gather), then x1f + yb (ptsb dead)
    // region B [16.78MB, 37.75MB): featf
    // region C: W1f, W2f, stats
    unsigned short* ptsb  = (unsigned short*)ws;                   // 16,777,216 B
    unsigned short* x1f   = (unsigned short*)ws;                   //  8,388,608 B
    unsigned short* yb    = (unsigned short*)(ws + 8388608);       //  8,388,608 B
    unsigned short* featf = (unsigned short*)(ws + 16777216);      // 20,971,520 B
    unsigned short* W1f   = (unsigned short*)(ws + 37748736);      //     81,920 B
    unsigned short* W2f   = (unsigned short*)(ws + 37830656);      //     32,768 B
    float*          st    = (float*)(ws + 37863424);               //      2,048 B

    prep_kernel<<<32768 + 224, 256, 0, stream>>>(points, xyz, W1, W2,
                                                 ptsb, W1f, W2f, st);
    gather_kernel<<<M_ROWS / 4, 256, 0, stream>>>(ptsb, xyz, lc, nl, didx, featf, out);
    gemm1_mfma<<<M_ROWS / 64, 256, 0, stream>>>(featf, W1f, b1, x1f, st, st + 128);
    gemm2_mfma<<<M_ROWS / 64, 256, 0, stream>>>(x1f, st, st + 128, g1, be1,
                                                W2f, b2, yb, st + 256, st + 384);
    out_kernel<<<(M_ROWS * C_OUT) / (256 * 8), 256, 0, stream>>>(
        yb, st + 256, st + 384, g2, be2, out + (size_t)M_ROWS * 3);
}

// Round 8
// 168.383 us; speedup vs baseline: 1.5503x; 1.1882x over previous
//
#include <hip/hip_runtime.h>
#include <hip/hip_bf16.h>
#include <math.h>

// Problem constants (from reference)
#define B_SZ     16
#define N_PTS    8192
#define NPOINT   2048
#define KNBR     32
#define D_FEAT   61
#define C_IN     64            // D_FEAT + 3
#define P_BINS   5
#define C_OUT    128
#define M_ROWS   (B_SZ * NPOINT)          // 32768
#define K1       (C_IN * P_BINS)          // 320
#define EPSV     1e-5f

typedef __attribute__((ext_vector_type(8))) short bf16x8;
typedef __attribute__((ext_vector_type(4))) float f32x4;

__device__ __forceinline__ unsigned short f2bf_rne(float v) {
    unsigned u = __float_as_uint(v);
    u += 0x7fffu + ((u >> 16) & 1u);
    return (unsigned short)(u >> 16);
}
__device__ __forceinline__ float bf2f(unsigned short v) {
    return __uint_as_float(((unsigned)v) << 16);
}

// Fragment-major B-side index (16x16x32 MFMA), chunk = 512 elems:
//   idx = ((c>>5)*8 + (n>>4))*512 + (((c>>3)&3)*16 + (n&15))*8 + (c&7)
__device__ __forceinline__ size_t fragB_idx(int n, int c) {
    return ((size_t)((c >> 5) * 8 + (n >> 4)) << 9) +
           ((((c >> 3) & 3) * 16 + (n & 15)) << 3) + (c & 7);
}

// ---------------------------------------------------------------------------
// Prep (tiny): W1,W2 -> fragment-major bf16; zero 4096-float stats replicas.
// st layout: [0,1024) sum1[8][128]; [1024,2048) sq1; [2048,3072) sum2;
//            [3072,4096) sq2.
// ---------------------------------------------------------------------------
__global__ __launch_bounds__(256) void prep_kernel(
    const float* __restrict__ W1, const float* __restrict__ W2,
    unsigned short* __restrict__ W1f, unsigned short* __restrict__ W2f,
    float* __restrict__ st)
{
    const int gid = blockIdx.x * 256 + threadIdx.x;     // grid 240 -> 61440
    if (gid < 40960) {
        int c = gid >> 7, n = gid & 127;
        W1f[fragB_idx(n, c)] = f2bf_rne(W1[gid]);
    } else if (gid < 57344) {
        int i = gid - 40960;
        int c = i >> 7, n = i & 127;
        W2f[fragB_idx(n, c)] = f2bf_rne(W2[i]);
    } else if (gid < 61440) {
        st[gid - 57344] = 0.f;
    }
}

// ---------------------------------------------------------------------------
// Fused gather + GEMM1 + BN1-stats.
// Block = 16 points = one 16-row tile. Wave w gathers points 4w..4w+3:
//   ballot counting-sort by radial bin; 32 SGPR-base f32 row loads
//   (lane=channel, direct from points/xyz, L2-resident per-batch slice);
//   register prefix accumulation; bf16 A-fragments into LDS.
// Barrier, then wave w computes cols [32w,32w+32) of x1 = feat@W1 + b1,
// stores x1 fragment-major (KCH=4), accumulates per-col sum/sumsq into
// 8-replica stats (replica = blockIdx&7).
// ---------------------------------------------------------------------------
__global__ __launch_bounds__(256) void fusedg1_kernel(
    const float* __restrict__ xyz, const float* __restrict__ points,
    const float* __restrict__ lc, const int* __restrict__ nl,
    const int* __restrict__ didx, const unsigned short* __restrict__ W1f,
    const float* __restrict__ b1, unsigned short* __restrict__ x1f,
    float* __restrict__ st, float* __restrict__ newxyz)
{
    const int g    = blockIdx.x;            // 0..2047
    const int xcd  = g & 7;
    const int slot = g >> 3;                // 0..255
    const int b    = 2 * xcd + (slot >> 7); // batch -> XCD b/2
    const int t16  = slot & 127;            // tile within batch
    const int tile = b * 128 + t16;         // global 16-row tile
    const int wave = threadIdx.x >> 6;
    const int lane = threadIdx.x & 63;
    const int k    = lane & 31;
    const int lm   = lane & 15, kg = lane >> 4;
    const int kgl  = (lane >> 3) & 3, jl = lane & 7, khalf = lane >> 5;

    __shared__ int s_srt[4][32];
    __shared__ __align__(16) unsigned short sA[10 * 512];   // 10 KB A tile

    const float* __restrict__ pbase = points + (size_t)b * N_PTS * D_FEAT;
    const float* __restrict__ xbase = xyz + (size_t)b * N_PTS * 3;

    for (int p = 0; p < 4; ++p) {
        const int mloc = wave * 4 + p;           // row within tile
        const int bid  = tile * 16 + mloc;       // global row
        const size_t nbase = (size_t)bid * KNBR;

        const float x = lc[(nbase + k) * 3 + 0];
        const float y = lc[(nbase + k) * 3 + 1];
        const float dd = fminf(sqrtf(x * x + y * y) * (1.0f / 1.5f), 0.99f);
        int bin = (int)(dd * 5.0f);
        bin = bin > 4 ? 4 : (bin < 0 ? 0 : bin);
        const int n = nl[nbase + k];

        unsigned m0 = (unsigned)__ballot(bin == 0);
        unsigned m1 = (unsigned)__ballot(bin == 1);
        unsigned m2 = (unsigned)__ballot(bin == 2);
        unsigned m3 = (unsigned)__ballot(bin == 3);
        unsigned m4 = (unsigned)__ballot(bin == 4);
        const int c0n = __popc(m0), c1n = __popc(m1);
        const int c2n = __popc(m2), c3n = __popc(m3);
        const int e0 = c0n, e1 = e0 + c1n, e2 = e1 + c2n, e3 = e2 + c3n;

        int start = (bin > 0 ? c0n : 0) + (bin > 1 ? c1n : 0) +
                    (bin > 2 ? c2n : 0) + (bin > 3 ? c3n : 0);
        unsigned mymask = m0;
        mymask = bin == 1 ? m1 : mymask;
        mymask = bin == 2 ? m2 : mymask;
        mymask = bin == 3 ? m3 : mymask;
        mymask = bin == 4 ? m4 : mymask;
        const int pos = start + __popc(mymask & ((1u << k) - 1u));

        if (lane < 32) s_srt[wave][pos] = n;
        if (lane >= 32 && lane < 35) {
            const int di = didx[bid];
            newxyz[(size_t)bid * 3 + (lane - 32)] = xbase[(size_t)di * 3 + (lane - 32)];
        }

        // 32 independent SGPR-base row loads, lane = channel
        float v[32];
        #pragma unroll
        for (int kk = 0; kk < 32; ++kk) {
            const int nr = __builtin_amdgcn_readfirstlane(s_srt[wave][kk]);
            float t;
            if (lane < D_FEAT) t = pbase[nr * D_FEAT + lane];
            else               t = xbase[nr * 3 + (lane - D_FEAT)];
            v[kk] = t;
        }

        // prefix accumulation; bin sums = prefix differences
        float acc = 0.f, pre0 = 0.f, pre1 = 0.f, pre2 = 0.f, pre3 = 0.f;
        #pragma unroll
        for (int kk = 0; kk < 32; ++kk) {
            acc += v[kk];
            const int kp = kk + 1;
            if (kp == e0) pre0 = acc;
            if (kp == e1) pre1 = acc;
            if (kp == e2) pre2 = acc;
            if (kp == e3) pre3 = acc;
        }
        float vals[5];
        vals[0] = pre0;
        vals[1] = pre1 - pre0;
        vals[2] = pre2 - pre1;
        vals[3] = pre3 - pre2;
        vals[4] = acc - pre3;

        // A-fragment writes into LDS (ch c = bb*64 + lane, row = mloc)
        #pragma unroll
        for (int bb = 0; bb < 5; ++bb) {
            const int kb = bb * 2 + khalf;
            sA[kb * 512 + (kgl * 16 + mloc) * 8 + jl] = f2bf_rne(vals[bb]);
        }
    }
    __syncthreads();

    // GEMM phase: wave w -> cols [32w, 32w+32)
    f32x4 acc0 = {}, acc1 = {};
    #pragma unroll
    for (int kb = 0; kb < 10; ++kb) {
        bf16x8 a = *(const bf16x8*)&sA[kb * 512 + lane * 8];
        bf16x8 w0 = *(const bf16x8*)(W1f + ((size_t)(kb * 8 + wave * 2) << 9) + lane * 8);
        bf16x8 w1 = *(const bf16x8*)(W1f + ((size_t)(kb * 8 + wave * 2 + 1) << 9) + lane * 8);
        acc0 = __builtin_amdgcn_mfma_f32_16x16x32_bf16(a, w0, acc0, 0, 0, 0);
        acc1 = __builtin_amdgcn_mfma_f32_16x16x32_bf16(a, w1, acc1, 0, 0, 0);
    }

    const int rep = (g & 7) * 128;
    #pragma unroll
    for (int q = 0; q < 2; ++q) {
        const f32x4 A = q ? acc1 : acc0;
        const int col = (wave * 2 + q) * 16 + lm;
        const float bb = b1[col];
        float ls = 0.f, lq = 0.f;
        #pragma unroll
        for (int i = 0; i < 4; ++i) {
            float vv = A[i] + bb;
            const size_t idx = (((size_t)(tile * 4 + (col >> 5))) << 9) +
                               ((((col >> 3) & 3) * 16 + kg * 4 + i) << 3) + (col & 7);
            x1f[idx] = f2bf_rne(vv);
            ls += vv; lq += vv * vv;
        }
        ls += __shfl_xor(ls, 16); ls += __shfl_xor(ls, 32);
        lq += __shfl_xor(lq, 16); lq += __shfl_xor(lq, 32);
        if (kg == 0) {
            atomicAdd(&st[rep + col], ls);
            atomicAdd(&st[1024 + rep + col], lq);
        }
    }
}

// ---------------------------------------------------------------------------
// GEMM2 (MFMA bf16): y = relu(BN1(x1)) @ W2 + b2, BN1 fused into A-frag load.
// A from x1 frag-major (KCH=4), B from W2 frag-major. y row-major bf16.
// BN2 stats into 8-replica block.
// ---------------------------------------------------------------------------
__global__ __launch_bounds__(256) void gemm2_mfma(
    const unsigned short* __restrict__ Xf,
    const float* __restrict__ st_in,
    const float* __restrict__ g1, const float* __restrict__ be1,
    const unsigned short* __restrict__ Wf, const float* __restrict__ bias,
    unsigned short* __restrict__ out, float* __restrict__ st)
{
    __shared__ float sc[128], sh[128];
    __shared__ float s_s[4][128], s_q[4][128];
    const int tid = threadIdx.x;
    if (tid < 128) {
        float s = 0.f, q = 0.f;
        #pragma unroll
        for (int r = 0; r < 8; ++r) {
            s += st_in[r * 128 + tid];
            q += st_in[1024 + r * 128 + tid];
        }
        float mu  = s * (1.0f / (float)M_ROWS);
        float var = q * (1.0f / (float)M_ROWS) - mu * mu;
        float iv  = 1.0f / sqrtf(var + EPSV);
        float sg  = g1[tid] * iv;
        sc[tid] = sg;
        sh[tid] = be1[tid] - mu * sg;
    }
    __syncthreads();

    const int g    = blockIdx.x;
    const int xcd  = g & 7;
    const int slot = g >> 3;
    const int bb_  = 2 * xcd + (slot >> 5);
    const int tile = (bb_ * 32 + (slot & 31)) * 4 + (tid >> 6);

    const int wave = tid >> 6, lane = tid & 63;
    const int lm = lane & 15, kg = lane >> 4;

    f32x4 acc[8] = {};
    #pragma unroll
    for (int kb = 0; kb < 4; ++kb) {
        const int c0 = kb * 32 + kg * 8;
        bf16x8 xr = *(const bf16x8*)(Xf + (((size_t)(tile * 4 + kb)) << 9) + lane * 8);
        f32x4 s0 = *(const f32x4*)&sc[c0];
        f32x4 s1 = *(const f32x4*)&sc[c0 + 4];
        f32x4 h0 = *(const f32x4*)&sh[c0];
        f32x4 h1 = *(const f32x4*)&sh[c0 + 4];
        bf16x8 a;
        #pragma unroll
        for (int j = 0; j < 4; ++j) {
            a[j]     = (short)f2bf_rne(fmaxf(0.f, s0[j] * bf2f((unsigned short)xr[j]) + h0[j]));
            a[4 + j] = (short)f2bf_rne(fmaxf(0.f, s1[j] * bf2f((unsigned short)xr[4 + j]) + h1[j]));
        }
        #pragma unroll
        for (int nf = 0; nf < 8; ++nf) {
            bf16x8 bfr = *(const bf16x8*)(Wf + (((size_t)(kb * 8 + nf)) << 9) + lane * 8);
            acc[nf] = __builtin_amdgcn_mfma_f32_16x16x32_bf16(a, bfr, acc[nf], 0, 0, 0);
        }
    }

    const int orow = tile * 16 + kg * 4;
    #pragma unroll
    for (int nf = 0; nf < 8; ++nf) {
        const int col = nf * 16 + lm;
        const float bb = bias[col];
        float ls = 0.f, lq = 0.f;
        #pragma unroll
        for (int i = 0; i < 4; ++i) {
            float v = acc[nf][i] + bb;
            out[(size_t)(orow + i) * C_OUT + col] = f2bf_rne(v);
            ls += v; lq += v * v;
        }
        ls += __shfl_xor(ls, 16); ls += __shfl_xor(ls, 32);
        lq += __shfl_xor(lq, 16); lq += __shfl_xor(lq, 32);
        if (kg == 0) { s_s[wave][col] = ls; s_q[wave][col] = lq; }
    }
    __syncthreads();
    if (tid < 128) {
        const int rep = (g & 7) * 128;
        float ts = s_s[0][tid] + s_s[1][tid] + s_s[2][tid] + s_s[3][tid];
        float tq = s_q[0][tid] + s_q[1][tid] + s_q[2][tid] + s_q[3][tid];
        atomicAdd(&st[2048 + rep + tid], ts);
        atomicAdd(&st[3072 + rep + tid], tq);
    }
}

// ---------------------------------------------------------------------------
// Final: new_points = relu(BN2(y)), y bf16 row-major, out f32.
// ---------------------------------------------------------------------------
__global__ __launch_bounds__(256) void out_kernel(
    const unsigned short* __restrict__ Y, const float* __restrict__ st,
    const float* __restrict__ g2, const float* __restrict__ be2,
    float* __restrict__ out)
{
    __shared__ float sc[128], sh[128];
    const int tid = threadIdx.x;
    if (tid < 128) {
        float s = 0.f, q = 0.f;
        #pragma unroll
        for (int r = 0; r < 8; ++r) {
            s += st[2048 + r * 128 + tid];
            q += st[3072 + r * 128 + tid];
        }
        float mu  = s * (1.0f / (float)M_ROWS);
        float var = q * (1.0f / (float)M_ROWS) - mu * mu;
        float iv  = 1.0f / sqrtf(var + EPSV);
        float sg  = g2[tid] * iv;
        sc[tid] = sg;
        sh[tid] = be2[tid] - mu * sg;
    }
    __syncthreads();

    const size_t e8 = (size_t)blockIdx.x * 256 + tid;   // ushort8 index
    bf16x8 v = ((const bf16x8*)Y)[e8];
    const int cb = (int)((e8 * 8) & 127);
    float4 r0, r1;
    r0.x = fmaxf(0.f, sc[cb + 0] * bf2f((unsigned short)v[0]) + sh[cb + 0]);
    r0.y = fmaxf(0.f, sc[cb + 1] * bf2f((unsigned short)v[1]) + sh[cb + 1]);
    r0.z = fmaxf(0.f, sc[cb + 2] * bf2f((unsigned short)v[2]) + sh[cb + 2]);
    r0.w = fmaxf(0.f, sc[cb + 3] * bf2f((unsigned short)v[3]) + sh[cb + 3]);
    r1.x = fmaxf(0.f, sc[cb + 4] * bf2f((unsigned short)v[4]) + sh[cb + 4]);
    r1.y = fmaxf(0.f, sc[cb + 5] * bf2f((unsigned short)v[5]) + sh[cb + 5]);
    r1.z = fmaxf(0.f, sc[cb + 6] * bf2f((unsigned short)v[6]) + sh[cb + 6]);
    r1.w = fmaxf(0.f, sc[cb + 7] * bf2f((unsigned short)v[7]) + sh[cb + 7]);
    ((float4*)out)[e8 * 2]     = r0;
    ((float4*)out)[e8 * 2 + 1] = r1;
}

// ---------------------------------------------------------------------------
extern "C" void kernel_launch(void* const* d_in, const int* in_sizes, int n_in,
                              void* d_out, int out_size, void* d_ws, size_t ws_size,
                              hipStream_t stream)
{
    const float* xyz    = (const float*)d_in[0];
    const float* points = (const float*)d_in[1];
    const float* lc     = (const float*)d_in[2];
    const int*   nl     = (const int*)d_in[3];
    // d_in[4] parameter_list: unused
    const int*   didx   = (const int*)d_in[5];
    const float* W1     = (const float*)d_in[6];
    const float* b1     = (const float*)d_in[7];
    const float* g1     = (const float*)d_in[8];
    const float* be1    = (const float*)d_in[9];
    const float* W2     = (const float*)d_in[10];
    const float* b2     = (const float*)d_in[11];
    const float* g2     = (const float*)d_in[12];
    const float* be2    = (const float*)d_in[13];

    float* out = (float*)d_out;
    char*  ws  = (char*)d_ws;

    // workspace layout (bytes):
    unsigned short* x1f = (unsigned short*)ws;                    //  8,388,608 B
    unsigned short* yb  = (unsigned short*)(ws + 8388608);        //  8,388,608 B
    unsigned short* W1f = (unsigned short*)(ws + 16777216);       //     81,920 B
    unsigned short* W2f = (unsigned short*)(ws + 16859136);       //     32,768 B
    float*          st  = (float*)(ws + 16891904);                //     16,384 B

    prep_kernel<<<240, 256, 0, stream>>>(W1, W2, W1f, W2f, st);
    fusedg1_kernel<<<M_ROWS / 16, 256, 0, stream>>>(xyz, points, lc, nl, didx,
                                                    W1f, b1, x1f, st, out);
    gemm2_mfma<<<M_ROWS / 64, 256, 0, stream>>>(x1f, st, g1, be1,
                                                W2f, b2, yb, st);
    out_kernel<<<(M_ROWS * C_OUT) / (256 * 8), 256, 0, stream>>>(
        yb, st, g2, be2, out + (size_t)M_ROWS * 3);
}